// Round 3
// baseline (2348.022 us; speedup 1.0000x reference)
//
#include <hip/hip_runtime.h>

typedef unsigned short u16;
typedef __attribute__((ext_vector_type(8))) short short8;
typedef __attribute__((ext_vector_type(16))) float f32x16;

__device__ inline u16 f2bf(float f){
  unsigned int u = __builtin_bit_cast(unsigned int, f);
  u += 0x7fffu + ((u >> 16) & 1u);
  return (u16)(u >> 16);
}
__device__ inline float bf2f(u16 h){
  unsigned int u = ((unsigned int)h) << 16;
  return __builtin_bit_cast(float, u);
}

typedef __attribute__((address_space(1))) const void* as1_t;
typedef __attribute__((address_space(3))) void* as3_t;
__device__ __forceinline__ void gload16(const u16* g, u16* l) {
  __builtin_amdgcn_global_load_lds((as1_t)g, (as3_t)l, 16, 0, 0);
}

// ---------------- weight transpose + cast:  W[K,N] f32 -> Wt[N,Kpad] bf16 ----
__global__ __launch_bounds__(256) void transpose_cast(
    const float* __restrict__ W, u16* __restrict__ Wt, int K, int N, int Kpad)
{
  __shared__ float tile[32][33];
  int k0 = blockIdx.x * 32, n0 = blockIdx.y * 32;
  int tx = threadIdx.x & 31, ty = threadIdx.x >> 5;   // ty 0..7
#pragma unroll
  for (int i = 0; i < 4; ++i) {
    int k = k0 + ty + i * 8;
    float v = 0.f;
    if (k < K && (n0 + tx) < N) v = W[(size_t)k * N + n0 + tx];
    tile[ty + i * 8][tx] = v;
  }
  __syncthreads();
#pragma unroll
  for (int i = 0; i < 4; ++i) {
    int nn = n0 + ty + i * 8;
    if (nn < N) Wt[(size_t)nn * Kpad + k0 + tx] = f2bf(tile[tx][ty + i * 8]);
  }
}

// ---------------- x cast with K padding -------------------------------------
__global__ void cast_pad(const float* __restrict__ x, u16* __restrict__ xb,
                         int R, int C, int Cp)
{
  int i = blockIdx.x * 256 + threadIdx.x;
  if (i >= R * Cp) return;
  int r = i / Cp, c = i % Cp;
  xb[i] = f2bf(c < C ? x[(size_t)r * C + c] : 0.f);
}

// ---------------- bf16 MFMA GEMM: C[M,N] = A[M,K] @ Bt[N,K]^T ---------------
// m97 staging (global_load_lds w16, linear [128][32] LDS) + 32x32x16 MFMA +
// LDS-staged coalesced bf16 epilogue (16B stores).
__global__ __launch_bounds__(256) void gemm_bt(
    const u16* __restrict__ A, const u16* __restrict__ B,
    float* __restrict__ Cf, u16* __restrict__ Cb,
    const float* __restrict__ bias, int M, int N, int K, int relu)
{
  __shared__ alignas(16) u16 lds[8448];   // As[4096] | Bs[4096]; epi reuses 64*132
  u16* As = lds;
  u16* Bs = lds + 4096;
  int tid = threadIdx.x;
  int wave = tid >> 6, lane = tid & 63;
  int wr = wave >> 1, wc = wave & 1;
  int tile_m = blockIdx.y * 128, tile_n = blockIdx.x * 128;

  // DMA staging: wave w writes LDS bytes [i*4096 + w*1024 + lane*16].
  int sr = wave * 16 + (lane >> 2);
  int sc = (lane & 3) * 8;
  const u16* gA0 = A + (size_t)(tile_m + sr) * K + sc;
  const u16* gA1 = A + (size_t)(tile_m + 64 + sr) * K + sc;
  const u16* gB0 = B + (size_t)(tile_n + sr) * K + sc;
  const u16* gB1 = B + (size_t)(tile_n + 64 + sr) * K + sc;
  u16* lA0 = &As[wave * 512];
  u16* lA1 = &As[2048 + wave * 512];
  u16* lB0 = &Bs[wave * 512];
  u16* lB1 = &Bs[2048 + wave * 512];

  f32x16 acc[2][2];
#pragma unroll
  for (int i = 0; i < 2; ++i)
#pragma unroll
    for (int j = 0; j < 2; ++j)
#pragma unroll
      for (int q = 0; q < 16; ++q) acc[i][j][q] = 0.f;

  int l31 = lane & 31, lk8 = (lane >> 5) * 8;

  for (int k0 = 0; k0 < K; k0 += 32) {
    gload16(gA0 + k0, lA0);
    gload16(gA1 + k0, lA1);
    gload16(gB0 + k0, lB0);
    gload16(gB1 + k0, lB1);
    __syncthreads();
    short8 a[2][2], b[2][2];
#pragma unroll
    for (int rb = 0; rb < 2; ++rb)
#pragma unroll
      for (int kk = 0; kk < 2; ++kk) {
        a[rb][kk] = *reinterpret_cast<const short8*>(&As[(wr * 64 + rb * 32 + l31) * 32 + kk * 16 + lk8]);
        b[rb][kk] = *reinterpret_cast<const short8*>(&Bs[(wc * 64 + rb * 32 + l31) * 32 + kk * 16 + lk8]);
      }
#pragma unroll
    for (int rb = 0; rb < 2; ++rb)
#pragma unroll
      for (int cb = 0; cb < 2; ++cb)
#pragma unroll
        for (int kk = 0; kk < 2; ++kk)
          acc[rb][cb] = __builtin_amdgcn_mfma_f32_32x32x16_bf16(a[rb][kk], b[cb][kk], acc[rb][cb], 0, 0, 0);
    __syncthreads();
  }

  float bv[2];
#pragma unroll
  for (int cb = 0; cb < 2; ++cb)
    bv[cb] = bias ? bias[tile_n + wc * 64 + cb * 32 + l31] : 0.f;

  if (Cf) {
    // direct f32 store path (small GEMMs only)
#pragma unroll
    for (int rb = 0; rb < 2; ++rb)
#pragma unroll
      for (int cb = 0; cb < 2; ++cb)
#pragma unroll
        for (int rg = 0; rg < 16; ++rg) {
          int row = tile_m + wr * 64 + rb * 32 + (rg & 3) + 8 * (rg >> 2) + 4 * (lane >> 5);
          int col = tile_n + wc * 64 + cb * 32 + l31;
          if (row < M) {
            float v = acc[rb][cb][rg] + bv[cb];
            if (relu) v = fmaxf(v, 0.f);
            Cf[(size_t)row * N + col] = v;
          }
        }
    return;
  }

  // LDS-staged coalesced bf16 epilogue: two 64-row halves
#pragma unroll
  for (int h = 0; h < 2; ++h) {
    __syncthreads();
    if (wr == h) {
#pragma unroll
      for (int rb = 0; rb < 2; ++rb)
#pragma unroll
        for (int cb = 0; cb < 2; ++cb)
#pragma unroll
          for (int rg = 0; rg < 16; ++rg) {
            int r = rb * 32 + (rg & 3) + 8 * (rg >> 2) + 4 * (lane >> 5);  // 0..63
            int c = wc * 64 + cb * 32 + l31;
            float v = acc[rb][cb][rg] + bv[cb];
            if (relu) v = fmaxf(v, 0.f);
            lds[r * 132 + c] = f2bf(v);
          }
    }
    __syncthreads();
#pragma unroll
    for (int it = 0; it < 4; ++it) {
      int r = it * 16 + (tid >> 4);
      int ch = tid & 15;
      int grow = tile_m + h * 64 + r;
      if (grow < M)
        *reinterpret_cast<short8*>(Cb + (size_t)grow * N + tile_n + ch * 8) =
            *reinterpret_cast<const short8*>(&lds[r * 132 + ch * 8]);
    }
  }
}

// ---------------- attention scores: a_src/a_dst [N,4] -----------------------
__global__ __launch_bounds__(256) void attn_scores(
    const u16* __restrict__ h, const float* __restrict__ asrc,
    const float* __restrict__ adst, float* __restrict__ a_s, float* __restrict__ a_d)
{
  int n = blockIdx.x;
  int hh = threadIdx.x >> 6, lane = threadIdx.x & 63;
  const u16* hr = h + (size_t)n * 8192 + hh * 2048;
  const float* as = asrc + hh * 2048;
  const float* ad = adst + hh * 2048;
  float ssum = 0.f, dsum = 0.f;
#pragma unroll
  for (int i = 0; i < 4; ++i) {
    int c = lane * 8 + i * 512;
    short8 v = *reinterpret_cast<const short8*>(hr + c);
#pragma unroll
    for (int j = 0; j < 8; ++j) {
      float f = bf2f((u16)v[j]);
      ssum += f * as[c + j];
      dsum += f * ad[c + j];
    }
  }
  for (int off = 32; off; off >>= 1) {
    ssum += __shfl_down(ssum, off);
    dsum += __shfl_down(dsum, off);
  }
  if (lane == 0) { a_s[n * 4 + hh] = ssum; a_d[n * 4 + hh] = dsum; }
}

// ---------------- CSR build --------------------------------------------------
__global__ void zero_int(int* p, int n){ int i = blockIdx.x*256+threadIdx.x; if (i < n) p[i] = 0; }

__global__ void count_deg(const int* __restrict__ ei, int E, int Nn, int* __restrict__ deg){
  int e = blockIdx.x*256+threadIdx.x; if (e >= E + Nn) return;
  int d = (e < E) ? ei[E + e] : (e - E);
  atomicAdd(&deg[d], 1);
}

__global__ void scan_deg(const int* __restrict__ deg, int* __restrict__ row_st,
                         int* __restrict__ cursor, int Nn){
  __shared__ int partial[256];
  int tid = threadIdx.x;
  int chunk = (Nn + 255) / 256;
  int start = tid * chunk;
  int sum = 0;
  for (int i = 0; i < chunk; ++i) { int idx = start + i; if (idx < Nn) sum += deg[idx]; }
  partial[tid] = sum;
  __syncthreads();
  if (tid == 0) { int acc = 0; for (int i = 0; i < 256; ++i) { int t = partial[i]; partial[i] = acc; acc += t; } }
  __syncthreads();
  int acc = partial[tid];
  for (int i = 0; i < chunk; ++i) {
    int idx = start + i;
    if (idx < Nn) { row_st[idx] = acc; cursor[idx] = acc; acc += deg[idx]; }
  }
  if (tid == 255) row_st[Nn] = acc;
}

__global__ void scatter_edges(const int* __restrict__ ei, int E, int Nn,
                              int* __restrict__ cursor, int* __restrict__ srcs){
  int e = blockIdx.x*256+threadIdx.x; if (e >= E + Nn) return;
  int s = (e < E) ? ei[e]     : (e - E);
  int d = (e < E) ? ei[E + e] : (e - E);
  int pos = atomicAdd(&cursor[d], 1);
  srcs[pos] = s;
}

// ---------------- per-(node,head) edge softmax -------------------------------
__global__ void edge_softmax(const int* __restrict__ row_st, const int* __restrict__ srcs,
                             const float* __restrict__ a_s, const float* __restrict__ a_d,
                             float* __restrict__ alpha, int Nn){
  int t = blockIdx.x*256+threadIdx.x;
  if (t >= Nn * 4) return;
  int n = t >> 2, hh = t & 3;
  int b = row_st[n], e = row_st[n + 1];
  float ad = a_d[n * 4 + hh];
  float m = -1e30f;
  for (int p = b; p < e; ++p) {
    float x = a_s[srcs[p] * 4 + hh] + ad;
    x = x > 0.f ? x : 0.2f * x;
    alpha[p * 4 + hh] = x;
    m = fmaxf(m, x);
  }
  float ssum = 0.f;
  for (int p = b; p < e; ++p) {
    float ex = expf(alpha[p * 4 + hh] - m);
    alpha[p * 4 + hh] = ex;
    ssum += ex;
  }
  float inv = 1.f / (ssum + 1e-16f);
  for (int p = b; p < e; ++p) alpha[p * 4 + hh] *= inv;
}

// ---------------- aggregation: out[n] = sum alpha*h[src] + bias (bf16 out) ---
__global__ __launch_bounds__(256) void aggregate(
    const u16* __restrict__ h, const float* __restrict__ alpha,
    const int* __restrict__ row_st, const int* __restrict__ srcs,
    const float* __restrict__ bias, u16* __restrict__ out)
{
  int n = blockIdx.x, tid = threadIdx.x;
  float acc[32];
#pragma unroll
  for (int i = 0; i < 32; ++i) acc[i] = 0.f;
  int b = row_st[n], e = row_st[n + 1];
  for (int p = b; p < e; ++p) {
    int s = srcs[p];
    const u16* hr = h + (size_t)s * 8192;
    float al[4];
#pragma unroll
    for (int j = 0; j < 4; ++j) al[j] = alpha[p * 4 + j];
#pragma unroll
    for (int j = 0; j < 4; ++j) {
      short8 v = *reinterpret_cast<const short8*>(hr + (tid + j * 256) * 8);
      float a = al[j];
#pragma unroll
      for (int q = 0; q < 8; ++q) acc[j * 8 + q] += a * bf2f((u16)v[q]);
    }
  }
#pragma unroll
  for (int j = 0; j < 4; ++j) {
    int c0 = (tid + j * 256) * 8;
    short8 ov;
#pragma unroll
    for (int q = 0; q < 8; ++q) ov[q] = (short)f2bf(acc[j * 8 + q] + bias[c0 + q]);
    *reinterpret_cast<short8*>(out + (size_t)n * 8192 + c0) = ov;
  }
}

// ---------------- mean pool over sorted batch --------------------------------
__global__ __launch_bounds__(256) void pool_mean(
    const u16* __restrict__ hf, const int* __restrict__ batch,
    u16* __restrict__ g, int Nn)
{
  int gid = blockIdx.x, tid = threadIdx.x;
  int s1, s2;
  { int l = 0, h = Nn; while (l < h) { int m = (l + h) >> 1; if (batch[m] < gid) l = m + 1; else h = m; } s1 = l; }
  { int l = 0, h = Nn; while (l < h) { int m = (l + h) >> 1; if (batch[m] < gid + 1) l = m + 1; else h = m; } s2 = l; }
  float inv = 1.f / fmaxf((float)(s2 - s1), 1.f);
  float acc[8];
#pragma unroll
  for (int q = 0; q < 8; ++q) acc[q] = 0.f;
  for (int r = s1; r < s2; ++r) {
    short8 v = *reinterpret_cast<const short8*>(hf + (size_t)r * 2048 + tid * 8);
#pragma unroll
    for (int q = 0; q < 8; ++q) acc[q] += bf2f((u16)v[q]);
  }
  short8 ov;
#pragma unroll
  for (int q = 0; q < 8; ++q) ov[q] = (short)f2bf(acc[q] * inv);
  *reinterpret_cast<short8*>(g + (size_t)gid * 2048 + tid * 8) = ov;
}

// ---------------- layernorm over 768 ----------------------------------------
__global__ __launch_bounds__(256) void layernorm_768(
    const float* __restrict__ x, const float* __restrict__ gam,
    const float* __restrict__ bet, float* __restrict__ out)
{
  int row = blockIdx.x, tid = threadIdx.x, lane = tid & 63, w = tid >> 6;
  __shared__ float sh[8];
  float v0 = x[row * 768 + tid];
  float v1 = x[row * 768 + 256 + tid];
  float v2 = x[row * 768 + 512 + tid];
  float s = v0 + v1 + v2;
  for (int off = 32; off; off >>= 1) s += __shfl_down(s, off);
  if (lane == 0) sh[w] = s;
  __syncthreads();
  if (tid == 0) sh[4] = (sh[0] + sh[1] + sh[2] + sh[3]) / 768.f;
  __syncthreads();
  float mu = sh[4];
  float d0 = v0 - mu, d1 = v1 - mu, d2 = v2 - mu;
  float q = d0 * d0 + d1 * d1 + d2 * d2;
  for (int off = 32; off; off >>= 1) q += __shfl_down(q, off);
  if (lane == 0) sh[w] = q;
  __syncthreads();
  if (tid == 0) sh[5] = rsqrtf((sh[0] + sh[1] + sh[2] + sh[3]) / 768.f + 1e-5f);
  __syncthreads();
  float rstd = sh[5];
  out[row * 768 + tid]       = d0 * rstd * gam[tid]       + bet[tid];
  out[row * 768 + 256 + tid] = d1 * rstd * gam[256 + tid] + bet[256 + tid];
  out[row * 768 + 512 + tid] = d2 * rstd * gam[512 + tid] + bet[512 + tid];
}

// ============================================================================
extern "C" void kernel_launch(void* const* d_in, const int* in_sizes, int n_in,
                              void* d_out, int out_size, void* d_ws, size_t ws_size,
                              hipStream_t stream)
{
  const float* x     = (const float*)d_in[0];
  const int*   ei    = (const int*)d_in[1];
  const int*   batch = (const int*)d_in[2];
  const float* W[3]   = {(const float*)d_in[3], (const float*)d_in[9],  (const float*)d_in[15]};
  const float* asr[3] = {(const float*)d_in[4], (const float*)d_in[10], (const float*)d_in[16]};
  const float* ads[3] = {(const float*)d_in[5], (const float*)d_in[11], (const float*)d_in[17]};
  const float* bc[3]  = {(const float*)d_in[6], (const float*)d_in[12], (const float*)d_in[18]};
  const float* Wh[3]  = {(const float*)d_in[7], (const float*)d_in[13], (const float*)d_in[19]};
  const float* bh[3]  = {(const float*)d_in[8], (const float*)d_in[14], (const float*)d_in[20]};
  const float* Wm1 = (const float*)d_in[21];
  const float* bm1 = (const float*)d_in[22];
  const float* Wm2 = (const float*)d_in[23];
  const float* bm2 = (const float*)d_in[24];
  const float* lng = (const float*)d_in[25];
  const float* lnb = (const float*)d_in[26];
  float* out = (float*)d_out;

  int Nn = in_sizes[2];        // 5000
  int E  = in_sizes[1] / 2;    // 15000
  int ET = E + Nn;             // + self loops

  char* base = (char*)d_ws;
  size_t off = 0;
  auto alloc = [&](size_t b) -> char* { char* p = base + off; off = (off + b + 255) & ~(size_t)255; return p; };
  u16*  xb    = (u16*)alloc((size_t)Nn * 320 * 2);
  u16*  Wt    = (u16*)alloc((size_t)8192 * 2048 * 2);
  u16*  Wht   = (u16*)alloc((size_t)8192 * 2048 * 2);
  u16*  hb    = (u16*)alloc((size_t)Nn * 8192 * 2);
  u16*  ob    = (u16*)alloc((size_t)Nn * 8192 * 2);
  u16*  xlb   = (u16*)alloc((size_t)Nn * 2048 * 2);
  float* a_s  = (float*)alloc((size_t)Nn * 4 * 4);
  float* a_d  = (float*)alloc((size_t)Nn * 4 * 4);
  float* alpha= (float*)alloc((size_t)ET * 4 * 4);
  int*  deg   = (int*)alloc((size_t)(Nn + 1) * 4);
  int*  rowst = (int*)alloc((size_t)(Nn + 1) * 4);
  int*  cursor= (int*)alloc((size_t)(Nn + 1) * 4);
  int*  srcs  = (int*)alloc((size_t)ET * 4);
  u16*  g     = (u16*)alloc((size_t)128 * 2048 * 2);
  u16*  g2    = (u16*)alloc((size_t)128 * 2048 * 2);
  float* preln= (float*)alloc((size_t)128 * 768 * 4);

  // ---- CSR by dst (self loops appended) ----
  zero_int<<<(Nn + 255) / 256, 256, 0, stream>>>(deg, Nn);
  count_deg<<<(ET + 255) / 256, 256, 0, stream>>>(ei, E, Nn, deg);
  scan_deg<<<1, 256, 0, stream>>>(deg, rowst, cursor, Nn);
  scatter_edges<<<(ET + 255) / 256, 256, 0, stream>>>(ei, E, Nn, cursor, srcs);

  // ---- input cast (pad K 300->320) ----
  cast_pad<<<(Nn * 320 + 255) / 256, 256, 0, stream>>>(x, xb, Nn, 300, 320);

  const u16* act = xb;
  int mtiles = (Nn + 127) / 128;
  for (int l = 0; l < 3; ++l) {
    int Kp = (l == 0) ? 320 : 2048;
    transpose_cast<<<dim3(Kp / 32, 8192 / 32), 256, 0, stream>>>(W[l], Wt, (l == 0) ? 300 : 2048, 8192, Kp);
    gemm_bt<<<dim3(64, mtiles), 256, 0, stream>>>(act, Wt, nullptr, hb, nullptr, Nn, 8192, Kp, 0);
    attn_scores<<<Nn, 256, 0, stream>>>(hb, asr[l], ads[l], a_s, a_d);
    edge_softmax<<<(Nn * 4 + 255) / 256, 256, 0, stream>>>(rowst, srcs, a_s, a_d, alpha, Nn);
    aggregate<<<Nn, 256, 0, stream>>>(hb, alpha, rowst, srcs, bc[l], ob);
    transpose_cast<<<dim3(8192 / 32, 2048 / 32), 256, 0, stream>>>(Wh[l], Wht, 8192, 2048, 8192);
    gemm_bt<<<dim3(16, mtiles), 256, 0, stream>>>(ob, Wht, nullptr, xlb, bh[l], Nn, 2048, 8192, (l < 2) ? 1 : 0);
    act = xlb;
  }

  // ---- mean pool + MLP + LN ----
  pool_mean<<<128, 256, 0, stream>>>(xlb, batch, g, Nn);
  transpose_cast<<<dim3(2048 / 32, 2048 / 32), 256, 0, stream>>>(Wm1, Wt, 2048, 2048, 2048);
  gemm_bt<<<dim3(16, 1), 256, 0, stream>>>(g, Wt, nullptr, g2, bm1, 128, 2048, 2048, 1);
  transpose_cast<<<dim3(2048 / 32, 768 / 32), 256, 0, stream>>>(Wm2, Wht, 2048, 768, 2048);
  gemm_bt<<<dim3(6, 1), 256, 0, stream>>>(g2, Wht, preln, nullptr, bm2, 128, 768, 2048, 0);
  layernorm_768<<<128, 256, 0, stream>>>(preln, lng, lnb, out);
}

// Round 4
// 2028.503 us; speedup vs baseline: 1.1575x; 1.1575x over previous
//
#include <hip/hip_runtime.h>

typedef unsigned short u16;
typedef __attribute__((ext_vector_type(8))) short short8;
typedef __attribute__((ext_vector_type(4))) float f32x4;

__device__ inline u16 f2bf(float f){
  unsigned int u = __builtin_bit_cast(unsigned int, f);
  u += 0x7fffu + ((u >> 16) & 1u);
  return (u16)(u >> 16);
}
__device__ inline float bf2f(u16 h){
  unsigned int u = ((unsigned int)h) << 16;
  return __builtin_bit_cast(float, u);
}

typedef __attribute__((address_space(1))) const void* as1_t;
typedef __attribute__((address_space(3))) void* as3_t;
__device__ __forceinline__ void gload16(const u16* g, u16* l) {
  __builtin_amdgcn_global_load_lds((as1_t)g, (as3_t)l, 16, 0, 0);
}

// ---------------- weight transpose + cast:  W[K,N] f32 -> Wt[N,Kpad] bf16 ----
__global__ __launch_bounds__(256) void transpose_cast(
    const float* __restrict__ W, u16* __restrict__ Wt, int K, int N, int Kpad)
{
  __shared__ float tile[32][33];
  int k0 = blockIdx.x * 32, n0 = blockIdx.y * 32;
  int tx = threadIdx.x & 31, ty = threadIdx.x >> 5;   // ty 0..7
#pragma unroll
  for (int i = 0; i < 4; ++i) {
    int k = k0 + ty + i * 8;
    float v = 0.f;
    if (k < K && (n0 + tx) < N) v = W[(size_t)k * N + n0 + tx];
    tile[ty + i * 8][tx] = v;
  }
  __syncthreads();
#pragma unroll
  for (int i = 0; i < 4; ++i) {
    int nn = n0 + ty + i * 8;
    if (nn < N) Wt[(size_t)nn * Kpad + k0 + tx] = f2bf(tile[tx][ty + i * 8]);
  }
}

// ---------------- x cast with K padding -------------------------------------
__global__ void cast_pad(const float* __restrict__ x, u16* __restrict__ xb,
                         int R, int C, int Cp)
{
  int i = blockIdx.x * 256 + threadIdx.x;
  if (i >= R * Cp) return;
  int r = i / Cp, c = i % Cp;
  xb[i] = f2bf(c < C ? x[(size_t)r * C + c] : 0.f);
}

// ---------------- bf16 MFMA GEMM: C[M,N] = A[M,K] @ Bt[N,K]^T ---------------
// R2 structure (m97: global_load_lds w16, linear [128][32] LDS, 16x16x32 MFMA)
// + bijective XCD-chunked block swizzle (tile_n-major within each XCD chunk)
// so blocks sharing a B-tile co-reside on one XCD's L2.
__global__ __launch_bounds__(256) void gemm_bt(
    const u16* __restrict__ A, const u16* __restrict__ B,
    float* __restrict__ Cf, u16* __restrict__ Cb,
    const float* __restrict__ bias, int M, int N, int K, int relu)
{
  __shared__ alignas(16) u16 As[128 * 32];
  __shared__ alignas(16) u16 Bs[128 * 32];
  int tid = threadIdx.x;
  int wave = tid >> 6, lane = tid & 63;
  int wr = wave >> 1, wc = wave & 1;

  // --- bijective XCD swizzle (m204): orig -> chunked wg, tile_n-major ---
  int nwg = gridDim.x * gridDim.y;
  int orig = blockIdx.y * gridDim.x + blockIdx.x;
  int q = nwg >> 3, r = nwg & 7;
  int xcd = orig & 7, ii = orig >> 3;
  int wg = (xcd < r ? xcd * (q + 1) : r * (q + 1) + (xcd - r) * q) + ii;
  int tile_n = (wg / gridDim.y) * 128;
  int tile_m = (wg % gridDim.y) * 128;

  // DMA staging: wave w writes LDS bytes [i*4096 + w*1024 + lane*16].
  // LDS row = byte/64 -> row = i*64 + w*16 + lane/4, col = (lane&3)*8.
  int sr = wave * 16 + (lane >> 2);
  int sc = (lane & 3) * 8;
  const u16* gA0 = A + (size_t)(tile_m + sr) * K + sc;
  const u16* gA1 = A + (size_t)(tile_m + 64 + sr) * K + sc;
  const u16* gB0 = B + (size_t)(tile_n + sr) * K + sc;
  const u16* gB1 = B + (size_t)(tile_n + 64 + sr) * K + sc;
  u16* lA0 = &As[wave * 512];
  u16* lA1 = &As[2048 + wave * 512];
  u16* lB0 = &Bs[wave * 512];
  u16* lB1 = &Bs[2048 + wave * 512];

  f32x4 acc[4][4];
#pragma unroll
  for (int mi = 0; mi < 4; ++mi)
#pragma unroll
    for (int ni = 0; ni < 4; ++ni) { f32x4 z = {0.f,0.f,0.f,0.f}; acc[mi][ni] = z; }

  int lrow = lane & 15, lk = (lane >> 4) * 8;

  for (int k0 = 0; k0 < K; k0 += 32) {
    gload16(gA0 + k0, lA0);
    gload16(gA1 + k0, lA1);
    gload16(gB0 + k0, lB0);
    gload16(gB1 + k0, lB1);
    __syncthreads();
    short8 af[4], bfr[4];
#pragma unroll
    for (int mi = 0; mi < 4; ++mi)
      af[mi] = *reinterpret_cast<const short8*>(&As[(wr * 64 + mi * 16 + lrow) * 32 + lk]);
#pragma unroll
    for (int ni = 0; ni < 4; ++ni)
      bfr[ni] = *reinterpret_cast<const short8*>(&Bs[(wc * 64 + ni * 16 + lrow) * 32 + lk]);
#pragma unroll
    for (int mi = 0; mi < 4; ++mi)
#pragma unroll
      for (int ni = 0; ni < 4; ++ni)
        acc[mi][ni] = __builtin_amdgcn_mfma_f32_16x16x32_bf16(af[mi], bfr[ni], acc[mi][ni], 0, 0, 0);
    __syncthreads();
  }

  int rquad = (lane >> 4) * 4;
#pragma unroll
  for (int mi = 0; mi < 4; ++mi)
#pragma unroll
    for (int ni = 0; ni < 4; ++ni) {
      int col = tile_n + wc * 64 + ni * 16 + lrow;
      float bv = bias ? bias[col] : 0.f;
#pragma unroll
      for (int j = 0; j < 4; ++j) {
        int row = tile_m + wr * 64 + mi * 16 + rquad + j;
        if (row < M) {
          float v = acc[mi][ni][j] + bv;
          if (relu) v = fmaxf(v, 0.f);
          if (Cb) Cb[(size_t)row * N + col] = f2bf(v);
          else    Cf[(size_t)row * N + col] = v;
        }
      }
    }
}

// ---------------- attention scores: a_src/a_dst [N,4] -----------------------
__global__ __launch_bounds__(256) void attn_scores(
    const u16* __restrict__ h, const float* __restrict__ asrc,
    const float* __restrict__ adst, float* __restrict__ a_s, float* __restrict__ a_d)
{
  int n = blockIdx.x;
  int hh = threadIdx.x >> 6, lane = threadIdx.x & 63;
  const u16* hr = h + (size_t)n * 8192 + hh * 2048;
  const float* as = asrc + hh * 2048;
  const float* ad = adst + hh * 2048;
  float ssum = 0.f, dsum = 0.f;
#pragma unroll
  for (int i = 0; i < 4; ++i) {
    int c = lane * 8 + i * 512;
    short8 v = *reinterpret_cast<const short8*>(hr + c);
#pragma unroll
    for (int j = 0; j < 8; ++j) {
      float f = bf2f((u16)v[j]);
      ssum += f * as[c + j];
      dsum += f * ad[c + j];
    }
  }
  for (int off = 32; off; off >>= 1) {
    ssum += __shfl_down(ssum, off);
    dsum += __shfl_down(dsum, off);
  }
  if (lane == 0) { a_s[n * 4 + hh] = ssum; a_d[n * 4 + hh] = dsum; }
}

// ---------------- CSR build --------------------------------------------------
__global__ void zero_int(int* p, int n){ int i = blockIdx.x*256+threadIdx.x; if (i < n) p[i] = 0; }

__global__ void count_deg(const int* __restrict__ ei, int E, int Nn, int* __restrict__ deg){
  int e = blockIdx.x*256+threadIdx.x; if (e >= E + Nn) return;
  int d = (e < E) ? ei[E + e] : (e - E);
  atomicAdd(&deg[d], 1);
}

__global__ void scan_deg(const int* __restrict__ deg, int* __restrict__ row_st,
                         int* __restrict__ cursor, int Nn){
  __shared__ int partial[256];
  int tid = threadIdx.x;
  int chunk = (Nn + 255) / 256;
  int start = tid * chunk;
  int sum = 0;
  for (int i = 0; i < chunk; ++i) { int idx = start + i; if (idx < Nn) sum += deg[idx]; }
  partial[tid] = sum;
  __syncthreads();
  if (tid == 0) { int acc = 0; for (int i = 0; i < 256; ++i) { int t = partial[i]; partial[i] = acc; acc += t; } }
  __syncthreads();
  int acc = partial[tid];
  for (int i = 0; i < chunk; ++i) {
    int idx = start + i;
    if (idx < Nn) { row_st[idx] = acc; cursor[idx] = acc; acc += deg[idx]; }
  }
  if (tid == 255) row_st[Nn] = acc;
}

__global__ void scatter_edges(const int* __restrict__ ei, int E, int Nn,
                              int* __restrict__ cursor, int* __restrict__ srcs){
  int e = blockIdx.x*256+threadIdx.x; if (e >= E + Nn) return;
  int s = (e < E) ? ei[e]     : (e - E);
  int d = (e < E) ? ei[E + e] : (e - E);
  int pos = atomicAdd(&cursor[d], 1);
  srcs[pos] = s;
}

// ---------------- per-(node,head) edge softmax -------------------------------
__global__ void edge_softmax(const int* __restrict__ row_st, const int* __restrict__ srcs,
                             const float* __restrict__ a_s, const float* __restrict__ a_d,
                             float* __restrict__ alpha, int Nn){
  int t = blockIdx.x*256+threadIdx.x;
  if (t >= Nn * 4) return;
  int n = t >> 2, hh = t & 3;
  int b = row_st[n], e = row_st[n + 1];
  float ad = a_d[n * 4 + hh];
  float m = -1e30f;
  for (int p = b; p < e; ++p) {
    float x = a_s[srcs[p] * 4 + hh] + ad;
    x = x > 0.f ? x : 0.2f * x;
    alpha[p * 4 + hh] = x;
    m = fmaxf(m, x);
  }
  float ssum = 0.f;
  for (int p = b; p < e; ++p) {
    float ex = expf(alpha[p * 4 + hh] - m);
    alpha[p * 4 + hh] = ex;
    ssum += ex;
  }
  float inv = 1.f / (ssum + 1e-16f);
  for (int p = b; p < e; ++p) alpha[p * 4 + hh] *= inv;
}

// ---------------- aggregation: out[n, hh*2048:] = sum alpha*h[src] + bias ----
// one block per (node, head): 256 threads x 8 cols = 2048 cols
__global__ __launch_bounds__(256) void aggregate(
    const u16* __restrict__ h, const float* __restrict__ alpha,
    const int* __restrict__ row_st, const int* __restrict__ srcs,
    const float* __restrict__ bias, u16* __restrict__ out)
{
  int n = blockIdx.x, hh = blockIdx.y, tid = threadIdx.x;
  int c0 = hh * 2048 + tid * 8;
  float acc[8];
#pragma unroll
  for (int q = 0; q < 8; ++q) acc[q] = 0.f;
  int b = row_st[n], e = row_st[n + 1];
  for (int p = b; p < e; ++p) {
    int s = srcs[p];
    float a = alpha[p * 4 + hh];
    short8 v = *reinterpret_cast<const short8*>(h + (size_t)s * 8192 + c0);
#pragma unroll
    for (int q = 0; q < 8; ++q) acc[q] += a * bf2f((u16)v[q]);
  }
  short8 ov;
#pragma unroll
  for (int q = 0; q < 8; ++q) ov[q] = (short)f2bf(acc[q] + bias[c0 + q]);
  *reinterpret_cast<short8*>(out + (size_t)n * 8192 + c0) = ov;
}

// ---------------- mean pool over sorted batch --------------------------------
__global__ __launch_bounds__(256) void pool_mean(
    const u16* __restrict__ hf, const int* __restrict__ batch,
    u16* __restrict__ g, int Nn)
{
  int gid = blockIdx.x, tid = threadIdx.x;
  int s1, s2;
  { int l = 0, h = Nn; while (l < h) { int m = (l + h) >> 1; if (batch[m] < gid) l = m + 1; else h = m; } s1 = l; }
  { int l = 0, h = Nn; while (l < h) { int m = (l + h) >> 1; if (batch[m] < gid + 1) l = m + 1; else h = m; } s2 = l; }
  float inv = 1.f / fmaxf((float)(s2 - s1), 1.f);
  float acc[8];
#pragma unroll
  for (int q = 0; q < 8; ++q) acc[q] = 0.f;
  for (int r = s1; r < s2; ++r) {
    short8 v = *reinterpret_cast<const short8*>(hf + (size_t)r * 2048 + tid * 8);
#pragma unroll
    for (int q = 0; q < 8; ++q) acc[q] += bf2f((u16)v[q]);
  }
  short8 ov;
#pragma unroll
  for (int q = 0; q < 8; ++q) ov[q] = (short)f2bf(acc[q] * inv);
  *reinterpret_cast<short8*>(g + (size_t)gid * 2048 + tid * 8) = ov;
}

// ---------------- layernorm over 768 ----------------------------------------
__global__ __launch_bounds__(256) void layernorm_768(
    const float* __restrict__ x, const float* __restrict__ gam,
    const float* __restrict__ bet, float* __restrict__ out)
{
  int row = blockIdx.x, tid = threadIdx.x, lane = tid & 63, w = tid >> 6;
  __shared__ float sh[8];
  float v0 = x[row * 768 + tid];
  float v1 = x[row * 768 + 256 + tid];
  float v2 = x[row * 768 + 512 + tid];
  float s = v0 + v1 + v2;
  for (int off = 32; off; off >>= 1) s += __shfl_down(s, off);
  if (lane == 0) sh[w] = s;
  __syncthreads();
  if (tid == 0) sh[4] = (sh[0] + sh[1] + sh[2] + sh[3]) / 768.f;
  __syncthreads();
  float mu = sh[4];
  float d0 = v0 - mu, d1 = v1 - mu, d2 = v2 - mu;
  float q = d0 * d0 + d1 * d1 + d2 * d2;
  for (int off = 32; off; off >>= 1) q += __shfl_down(q, off);
  if (lane == 0) sh[w] = q;
  __syncthreads();
  if (tid == 0) sh[5] = rsqrtf((sh[0] + sh[1] + sh[2] + sh[3]) / 768.f + 1e-5f);
  __syncthreads();
  float rstd = sh[5];
  out[row * 768 + tid]       = d0 * rstd * gam[tid]       + bet[tid];
  out[row * 768 + 256 + tid] = d1 * rstd * gam[256 + tid] + bet[256 + tid];
  out[row * 768 + 512 + tid] = d2 * rstd * gam[512 + tid] + bet[512 + tid];
}

// ============================================================================
extern "C" void kernel_launch(void* const* d_in, const int* in_sizes, int n_in,
                              void* d_out, int out_size, void* d_ws, size_t ws_size,
                              hipStream_t stream)
{
  const float* x     = (const float*)d_in[0];
  const int*   ei    = (const int*)d_in[1];
  const int*   batch = (const int*)d_in[2];
  const float* W[3]   = {(const float*)d_in[3], (const float*)d_in[9],  (const float*)d_in[15]};
  const float* asr[3] = {(const float*)d_in[4], (const float*)d_in[10], (const float*)d_in[16]};
  const float* ads[3] = {(const float*)d_in[5], (const float*)d_in[11], (const float*)d_in[17]};
  const float* bc[3]  = {(const float*)d_in[6], (const float*)d_in[12], (const float*)d_in[18]};
  const float* Wh[3]  = {(const float*)d_in[7], (const float*)d_in[13], (const float*)d_in[19]};
  const float* bh[3]  = {(const float*)d_in[8], (const float*)d_in[14], (const float*)d_in[20]};
  const float* Wm1 = (const float*)d_in[21];
  const float* bm1 = (const float*)d_in[22];
  const float* Wm2 = (const float*)d_in[23];
  const float* bm2 = (const float*)d_in[24];
  const float* lng = (const float*)d_in[25];
  const float* lnb = (const float*)d_in[26];
  float* out = (float*)d_out;

  int Nn = in_sizes[2];        // 5000
  int E  = in_sizes[1] / 2;    // 15000
  int ET = E + Nn;             // + self loops

  char* base = (char*)d_ws;
  size_t off = 0;
  auto alloc = [&](size_t b) -> char* { char* p = base + off; off = (off + b + 255) & ~(size_t)255; return p; };
  u16*  xb    = (u16*)alloc((size_t)Nn * 320 * 2);
  u16*  Wt    = (u16*)alloc((size_t)8192 * 2048 * 2);
  u16*  Wht   = (u16*)alloc((size_t)8192 * 2048 * 2);
  u16*  hb    = (u16*)alloc((size_t)Nn * 8192 * 2);
  u16*  ob    = (u16*)alloc((size_t)Nn * 8192 * 2);
  u16*  xlb   = (u16*)alloc((size_t)Nn * 2048 * 2);
  float* a_s  = (float*)alloc((size_t)Nn * 4 * 4);
  float* a_d  = (float*)alloc((size_t)Nn * 4 * 4);
  float* alpha= (float*)alloc((size_t)ET * 4 * 4);
  int*  deg   = (int*)alloc((size_t)(Nn + 1) * 4);
  int*  rowst = (int*)alloc((size_t)(Nn + 1) * 4);
  int*  cursor= (int*)alloc((size_t)(Nn + 1) * 4);
  int*  srcs  = (int*)alloc((size_t)ET * 4);
  u16*  g     = (u16*)alloc((size_t)128 * 2048 * 2);
  u16*  g2    = (u16*)alloc((size_t)128 * 2048 * 2);
  float* preln= (float*)alloc((size_t)128 * 768 * 4);

  // ---- CSR by dst (self loops appended) ----
  zero_int<<<(Nn + 255) / 256, 256, 0, stream>>>(deg, Nn);
  count_deg<<<(ET + 255) / 256, 256, 0, stream>>>(ei, E, Nn, deg);
  scan_deg<<<1, 256, 0, stream>>>(deg, rowst, cursor, Nn);
  scatter_edges<<<(ET + 255) / 256, 256, 0, stream>>>(ei, E, Nn, cursor, srcs);

  // ---- input cast (pad K 300->320) ----
  cast_pad<<<(Nn * 320 + 255) / 256, 256, 0, stream>>>(x, xb, Nn, 300, 320);

  const u16* act = xb;
  int mtiles = (Nn + 127) / 128;
  for (int l = 0; l < 3; ++l) {
    int Kp = (l == 0) ? 320 : 2048;
    transpose_cast<<<dim3(Kp / 32, 8192 / 32), 256, 0, stream>>>(W[l], Wt, (l == 0) ? 300 : 2048, 8192, Kp);
    gemm_bt<<<dim3(64, mtiles), 256, 0, stream>>>(act, Wt, nullptr, hb, nullptr, Nn, 8192, Kp, 0);
    attn_scores<<<Nn, 256, 0, stream>>>(hb, asr[l], ads[l], a_s, a_d);
    edge_softmax<<<(Nn * 4 + 255) / 256, 256, 0, stream>>>(rowst, srcs, a_s, a_d, alpha, Nn);
    aggregate<<<dim3(Nn, 4), 256, 0, stream>>>(hb, alpha, rowst, srcs, bc[l], ob);
    transpose_cast<<<dim3(8192 / 32, 2048 / 32), 256, 0, stream>>>(Wh[l], Wht, 8192, 2048, 8192);
    gemm_bt<<<dim3(16, mtiles), 256, 0, stream>>>(ob, Wht, nullptr, xlb, bh[l], Nn, 2048, 8192, (l < 2) ? 1 : 0);
    act = xlb;
  }

  // ---- mean pool + MLP + LN ----
  pool_mean<<<128, 256, 0, stream>>>(xlb, batch, g, Nn);
  transpose_cast<<<dim3(2048 / 32, 2048 / 32), 256, 0, stream>>>(Wm1, Wt, 2048, 2048, 2048);
  gemm_bt<<<dim3(16, 1), 256, 0, stream>>>(g, Wt, nullptr, g2, bm1, 128, 2048, 2048, 1);
  transpose_cast<<<dim3(2048 / 32, 768 / 32), 256, 0, stream>>>(Wm2, Wht, 2048, 768, 2048);
  gemm_bt<<<dim3(6, 1), 256, 0, stream>>>(g2, Wht, preln, nullptr, bm2, 128, 768, 2048, 0);
  layernorm_768<<<128, 256, 0, stream>>>(preln, lng, lnb, out);
}

// Round 5
// 1997.095 us; speedup vs baseline: 1.1757x; 1.0157x over previous
//
#include <hip/hip_runtime.h>

typedef unsigned short u16;
typedef __attribute__((ext_vector_type(8))) short short8;
typedef __attribute__((ext_vector_type(4))) float f32x4;

__device__ inline u16 f2bf(float f){
  unsigned int u = __builtin_bit_cast(unsigned int, f);
  u += 0x7fffu + ((u >> 16) & 1u);
  return (u16)(u >> 16);
}
__device__ inline float bf2f(u16 h){
  unsigned int u = ((unsigned int)h) << 16;
  return __builtin_bit_cast(float, u);
}

typedef __attribute__((address_space(1))) const void* as1_t;
typedef __attribute__((address_space(3))) void* as3_t;
__device__ __forceinline__ void gload16(const u16* g, u16* l) {
  __builtin_amdgcn_global_load_lds((as1_t)g, (as3_t)l, 16, 0, 0);
}

#define BARRIER() asm volatile("s_barrier" ::: "memory")
#define VMCNT4()  asm volatile("s_waitcnt vmcnt(4)" ::: "memory")
#define VMCNT0()  asm volatile("s_waitcnt vmcnt(0)" ::: "memory")
// XOR swizzle within a 16KB [256][64B] operand tile: spreads the 16-row
// column read across bank groups (2 lanes/group = free). Involution; keeps
// 16B chunks contiguous (touches byte-bits 4-5 only).
__device__ __forceinline__ int swz(int b) {
  return b ^ ((b >> 2) & 0x30) ^ ((b >> 4) & 0x30);
}

// ---------------- weight transpose + cast:  W[K,N] f32 -> Wt[N,Kpad] bf16 ----
__global__ __launch_bounds__(256) void transpose_cast(
    const float* __restrict__ W, u16* __restrict__ Wt, int K, int N, int Kpad)
{
  __shared__ float tile[32][33];
  int k0 = blockIdx.x * 32, n0 = blockIdx.y * 32;
  int tx = threadIdx.x & 31, ty = threadIdx.x >> 5;
#pragma unroll
  for (int i = 0; i < 4; ++i) {
    int k = k0 + ty + i * 8;
    float v = 0.f;
    if (k < K && (n0 + tx) < N) v = W[(size_t)k * N + n0 + tx];
    tile[ty + i * 8][tx] = v;
  }
  __syncthreads();
#pragma unroll
  for (int i = 0; i < 4; ++i) {
    int nn = n0 + ty + i * 8;
    if (nn < N) Wt[(size_t)nn * Kpad + k0 + tx] = f2bf(tile[tx][ty + i * 8]);
  }
}

// ---------------- x cast with K padding -------------------------------------
__global__ void cast_pad(const float* __restrict__ x, u16* __restrict__ xb,
                         int R, int C, int Cp)
{
  int i = blockIdx.x * 256 + threadIdx.x;
  if (i >= R * Cp) return;
  int r = i / Cp, c = i % Cp;
  xb[i] = f2bf(c < C ? x[(size_t)r * C + c] : 0.f);
}

// ================= 256x256 deep-pipelined GEMM (bf16 out) ====================
// C[M,N] = A[M,K] @ B[N,K]^T, K % 32 == 0, N % 256 == 0. 512 thr = 8 waves
// (2Mx4N), per-wave 128x64. BK=32, 3 LDS buffers, prefetch distance 2,
// counted vmcnt(4), 2 phases/K-tile with double s_barrier, XOR-swizzled LDS.
__global__ __launch_bounds__(512, 2) void gemm256(
    const u16* __restrict__ A, const u16* __restrict__ B,
    u16* __restrict__ C, const float* __restrict__ bias,
    int M, int N, int K, int relu)
{
  __shared__ alignas(16) u16 lds[3 * 16384];   // 3 bufs x (A 16KB | B 16KB)
  int tid = threadIdx.x;
  int wave = tid >> 6, lane = tid & 63;
  int wm = wave >> 2, wn = wave & 3;           // 2 x 4 wave grid
  int tile_m = blockIdx.y * 256, tile_n = blockIdx.x * 256;
  int NT = K >> 5;

  // ---- stage sources: chunk j = (op A/A/B/B, sweep 0/1/0/1) ----
  // LDS dest is linear (base + lane*16); global source is pre-swizzled.
  const u16* src[4];
  int ubase[4];
#pragma unroll
  for (int j = 0; j < 4; ++j) {
    int op = j >> 1, sw = j & 1;
    int L  = sw * 8192 + tid * 16;             // byte off in 16KB operand region
    int Ls = swz(L);
    int grow = Ls >> 6;                        // 0..255
    int gcol = (Ls & 63) >> 1;                 // 0..31 elements
    src[j] = (op ? B + (size_t)(tile_n + grow) * K
                 : A + (size_t)(tile_m + grow) * K) + gcol;
    ubase[j] = op * 8192 + sw * 4096 + wave * 512;   // wave-uniform u16 index
  }

  // ---- fragment read offsets (u16 index within buf, swizzled) ----
  int l15 = lane & 15, k16 = lane >> 4;
  int aoff[2][4], boff[4];
#pragma unroll
  for (int mh = 0; mh < 2; ++mh)
#pragma unroll
    for (int mi = 0; mi < 4; ++mi) {
      int row = wm * 128 + mh * 64 + mi * 16 + l15;
      aoff[mh][mi] = swz(row * 64 + k16 * 16) >> 1;
    }
#pragma unroll
  for (int ni = 0; ni < 4; ++ni) {
    int row = wn * 64 + ni * 16 + l15;
    boff[ni] = 8192 + (swz(row * 64 + k16 * 16) >> 1);
  }

  f32x4 acc[2][4][4];
#pragma unroll
  for (int mh = 0; mh < 2; ++mh)
#pragma unroll
    for (int mi = 0; mi < 4; ++mi)
#pragma unroll
      for (int ni = 0; ni < 4; ++ni) { f32x4 z = {0.f,0.f,0.f,0.f}; acc[mh][mi][ni] = z; }

  // ---- prologue: stage tiles 0 and 1 ----
#pragma unroll
  for (int j = 0; j < 4; ++j) gload16(src[j], &lds[ubase[j]]);
#pragma unroll
  for (int j = 0; j < 4; ++j) gload16(src[j] + 32, &lds[16384 + ubase[j]]);
  VMCNT4();        // tile 0 resident; tile 1 in flight
  BARRIER();

  for (int t = 0; t < NT; ++t) {
    int cb = (t % 3) * 16384;
    int nb = ((t + 2) % 3) * 16384;
    bool st = (t + 2) < NT;
    int kadv = (t + 2) * 32;
    // ---------------- phase 0: mh = 0 ----------------
    short8 a0 = *reinterpret_cast<const short8*>(&lds[cb + aoff[0][0]]);
    short8 a1 = *reinterpret_cast<const short8*>(&lds[cb + aoff[0][1]]);
    short8 a2 = *reinterpret_cast<const short8*>(&lds[cb + aoff[0][2]]);
    short8 a3 = *reinterpret_cast<const short8*>(&lds[cb + aoff[0][3]]);
    short8 b0 = *reinterpret_cast<const short8*>(&lds[cb + boff[0]]);
    short8 b1 = *reinterpret_cast<const short8*>(&lds[cb + boff[1]]);
    short8 b2 = *reinterpret_cast<const short8*>(&lds[cb + boff[2]]);
    short8 b3 = *reinterpret_cast<const short8*>(&lds[cb + boff[3]]);
    if (st) {
      gload16(src[0] + kadv, &lds[nb + ubase[0]]);
      gload16(src[1] + kadv, &lds[nb + ubase[1]]);
    }
    BARRIER();
    __builtin_amdgcn_s_setprio(1);
#pragma unroll
    for (int ni = 0; ni < 4; ++ni) {
      short8 bf = ni == 0 ? b0 : ni == 1 ? b1 : ni == 2 ? b2 : b3;
      acc[0][0][ni] = __builtin_amdgcn_mfma_f32_16x16x32_bf16(a0, bf, acc[0][0][ni], 0, 0, 0);
      acc[0][1][ni] = __builtin_amdgcn_mfma_f32_16x16x32_bf16(a1, bf, acc[0][1][ni], 0, 0, 0);
      acc[0][2][ni] = __builtin_amdgcn_mfma_f32_16x16x32_bf16(a2, bf, acc[0][2][ni], 0, 0, 0);
      acc[0][3][ni] = __builtin_amdgcn_mfma_f32_16x16x32_bf16(a3, bf, acc[0][3][ni], 0, 0, 0);
    }
    __builtin_amdgcn_s_setprio(0);
    BARRIER();
    // ---------------- phase 1: mh = 1 ----------------
    short8 a4 = *reinterpret_cast<const short8*>(&lds[cb + aoff[1][0]]);
    short8 a5 = *reinterpret_cast<const short8*>(&lds[cb + aoff[1][1]]);
    short8 a6 = *reinterpret_cast<const short8*>(&lds[cb + aoff[1][2]]);
    short8 a7 = *reinterpret_cast<const short8*>(&lds[cb + aoff[1][3]]);
    if (st) {
      gload16(src[2] + kadv, &lds[nb + ubase[2]]);
      gload16(src[3] + kadv, &lds[nb + ubase[3]]);
    }
    if (t < NT - 2) { VMCNT4(); }          // tile t+1 resident, t+2 in flight
    else if (t == NT - 2) { VMCNT0(); }    // last fill: drain tile NT-1
    BARRIER();
    __builtin_amdgcn_s_setprio(1);
#pragma unroll
    for (int ni = 0; ni < 4; ++ni) {
      short8 bf = ni == 0 ? b0 : ni == 1 ? b1 : ni == 2 ? b2 : b3;
      acc[1][0][ni] = __builtin_amdgcn_mfma_f32_16x16x32_bf16(a4, bf, acc[1][0][ni], 0, 0, 0);
      acc[1][1][ni] = __builtin_amdgcn_mfma_f32_16x16x32_bf16(a5, bf, acc[1][1][ni], 0, 0, 0);
      acc[1][2][ni] = __builtin_amdgcn_mfma_f32_16x16x32_bf16(a6, bf, acc[1][2][ni], 0, 0, 0);
      acc[1][3][ni] = __builtin_amdgcn_mfma_f32_16x16x32_bf16(a7, bf, acc[1][3][ni], 0, 0, 0);
    }
    __builtin_amdgcn_s_setprio(0);
    BARRIER();
  }

  // ---- epilogue: direct bf16 stores (C/D map: col=lane&15, row=(lane>>4)*4+j)
  int rq = (lane >> 4) * 4;
#pragma unroll
  for (int mh = 0; mh < 2; ++mh)
#pragma unroll
    for (int mi = 0; mi < 4; ++mi)
#pragma unroll
      for (int ni = 0; ni < 4; ++ni) {
        int col = tile_n + wn * 64 + ni * 16 + l15;
        float bv = bias ? bias[col] : 0.f;
#pragma unroll
        for (int j = 0; j < 4; ++j) {
          int row = tile_m + wm * 128 + mh * 64 + mi * 16 + rq + j;
          if (row < M) {
            float v = acc[mh][mi][ni][j] + bv;
            if (relu) v = fmaxf(v, 0.f);
            C[(size_t)row * N + col] = f2bf(v);
          }
        }
      }
}

// ---------------- 128x128 GEMM (R2 structure, small/f32 cases) ---------------
__global__ __launch_bounds__(256) void gemm_bt(
    const u16* __restrict__ A, const u16* __restrict__ B,
    float* __restrict__ Cf, u16* __restrict__ Cb,
    const float* __restrict__ bias, int M, int N, int K, int relu)
{
  __shared__ alignas(16) u16 As[128 * 32];
  __shared__ alignas(16) u16 Bs[128 * 32];
  int tid = threadIdx.x;
  int wave = tid >> 6, lane = tid & 63;
  int wr = wave >> 1, wc = wave & 1;
  int tile_m = blockIdx.y * 128, tile_n = blockIdx.x * 128;

  int sr = wave * 16 + (lane >> 2);
  int sc = (lane & 3) * 8;
  const u16* gA0 = A + (size_t)(tile_m + sr) * K + sc;
  const u16* gA1 = A + (size_t)(tile_m + 64 + sr) * K + sc;
  const u16* gB0 = B + (size_t)(tile_n + sr) * K + sc;
  const u16* gB1 = B + (size_t)(tile_n + 64 + sr) * K + sc;
  u16* lA0 = &As[wave * 512];
  u16* lA1 = &As[2048 + wave * 512];
  u16* lB0 = &Bs[wave * 512];
  u16* lB1 = &Bs[2048 + wave * 512];

  f32x4 acc[4][4];
#pragma unroll
  for (int mi = 0; mi < 4; ++mi)
#pragma unroll
    for (int ni = 0; ni < 4; ++ni) { f32x4 z = {0.f,0.f,0.f,0.f}; acc[mi][ni] = z; }

  int lrow = lane & 15, lk = (lane >> 4) * 8;

  for (int k0 = 0; k0 < K; k0 += 32) {
    gload16(gA0 + k0, lA0);
    gload16(gA1 + k0, lA1);
    gload16(gB0 + k0, lB0);
    gload16(gB1 + k0, lB1);
    __syncthreads();
    short8 af[4], bfr[4];
#pragma unroll
    for (int mi = 0; mi < 4; ++mi)
      af[mi] = *reinterpret_cast<const short8*>(&As[(wr * 64 + mi * 16 + lrow) * 32 + lk]);
#pragma unroll
    for (int ni = 0; ni < 4; ++ni)
      bfr[ni] = *reinterpret_cast<const short8*>(&Bs[(wc * 64 + ni * 16 + lrow) * 32 + lk]);
#pragma unroll
    for (int mi = 0; mi < 4; ++mi)
#pragma unroll
      for (int ni = 0; ni < 4; ++ni)
        acc[mi][ni] = __builtin_amdgcn_mfma_f32_16x16x32_bf16(af[mi], bfr[ni], acc[mi][ni], 0, 0, 0);
    __syncthreads();
  }

  int rquad = (lane >> 4) * 4;
#pragma unroll
  for (int mi = 0; mi < 4; ++mi)
#pragma unroll
    for (int ni = 0; ni < 4; ++ni) {
      int col = tile_n + wc * 64 + ni * 16 + lrow;
      float bv = bias ? bias[col] : 0.f;
#pragma unroll
      for (int j = 0; j < 4; ++j) {
        int row = tile_m + wr * 64 + mi * 16 + rquad + j;
        if (row < M) {
          float v = acc[mi][ni][j] + bv;
          if (relu) v = fmaxf(v, 0.f);
          if (Cb) Cb[(size_t)row * N + col] = f2bf(v);
          else    Cf[(size_t)row * N + col] = v;
        }
      }
    }
}

// ---------------- attention scores: a_src/a_dst [N,4] -----------------------
__global__ __launch_bounds__(256) void attn_scores(
    const u16* __restrict__ h, const float* __restrict__ asrc,
    const float* __restrict__ adst, float* __restrict__ a_s, float* __restrict__ a_d)
{
  int n = blockIdx.x;
  int hh = threadIdx.x >> 6, lane = threadIdx.x & 63;
  const u16* hr = h + (size_t)n * 8192 + hh * 2048;
  const float* as = asrc + hh * 2048;
  const float* ad = adst + hh * 2048;
  float ssum = 0.f, dsum = 0.f;
#pragma unroll
  for (int i = 0; i < 4; ++i) {
    int c = lane * 8 + i * 512;
    short8 v = *reinterpret_cast<const short8*>(hr + c);
#pragma unroll
    for (int j = 0; j < 8; ++j) {
      float f = bf2f((u16)v[j]);
      ssum += f * as[c + j];
      dsum += f * ad[c + j];
    }
  }
  for (int off = 32; off; off >>= 1) {
    ssum += __shfl_down(ssum, off);
    dsum += __shfl_down(dsum, off);
  }
  if (lane == 0) { a_s[n * 4 + hh] = ssum; a_d[n * 4 + hh] = dsum; }
}

// ---------------- CSR build --------------------------------------------------
__global__ void zero_int(int* p, int n){ int i = blockIdx.x*256+threadIdx.x; if (i < n) p[i] = 0; }

__global__ void count_deg(const int* __restrict__ ei, int E, int Nn, int* __restrict__ deg){
  int e = blockIdx.x*256+threadIdx.x; if (e >= E + Nn) return;
  int d = (e < E) ? ei[E + e] : (e - E);
  atomicAdd(&deg[d], 1);
}

__global__ void scan_deg(const int* __restrict__ deg, int* __restrict__ row_st,
                         int* __restrict__ cursor, int Nn){
  __shared__ int partial[256];
  int tid = threadIdx.x;
  int chunk = (Nn + 255) / 256;
  int start = tid * chunk;
  int sum = 0;
  for (int i = 0; i < chunk; ++i) { int idx = start + i; if (idx < Nn) sum += deg[idx]; }
  partial[tid] = sum;
  __syncthreads();
  if (tid == 0) { int acc = 0; for (int i = 0; i < 256; ++i) { int t = partial[i]; partial[i] = acc; acc += t; } }
  __syncthreads();
  int acc = partial[tid];
  for (int i = 0; i < chunk; ++i) {
    int idx = start + i;
    if (idx < Nn) { row_st[idx] = acc; cursor[idx] = acc; acc += deg[idx]; }
  }
  if (tid == 255) row_st[Nn] = acc;
}

__global__ void scatter_edges(const int* __restrict__ ei, int E, int Nn,
                              int* __restrict__ cursor, int* __restrict__ srcs){
  int e = blockIdx.x*256+threadIdx.x; if (e >= E + Nn) return;
  int s = (e < E) ? ei[e]     : (e - E);
  int d = (e < E) ? ei[E + e] : (e - E);
  int pos = atomicAdd(&cursor[d], 1);
  srcs[pos] = s;
}

// ---------------- per-(node,head) edge softmax -------------------------------
__global__ void edge_softmax(const int* __restrict__ row_st, const int* __restrict__ srcs,
                             const float* __restrict__ a_s, const float* __restrict__ a_d,
                             float* __restrict__ alpha, int Nn){
  int t = blockIdx.x*256+threadIdx.x;
  if (t >= Nn * 4) return;
  int n = t >> 2, hh = t & 3;
  int b = row_st[n], e = row_st[n + 1];
  float ad = a_d[n * 4 + hh];
  float m = -1e30f;
  for (int p = b; p < e; ++p) {
    float x = a_s[srcs[p] * 4 + hh] + ad;
    x = x > 0.f ? x : 0.2f * x;
    alpha[p * 4 + hh] = x;
    m = fmaxf(m, x);
  }
  float ssum = 0.f;
  for (int p = b; p < e; ++p) {
    float ex = expf(alpha[p * 4 + hh] - m);
    alpha[p * 4 + hh] = ex;
    ssum += ex;
  }
  float inv = 1.f / (ssum + 1e-16f);
  for (int p = b; p < e; ++p) alpha[p * 4 + hh] *= inv;
}

// ---------------- aggregation: out[n, hh*2048:] = sum alpha*h[src] + bias ----
__global__ __launch_bounds__(256) void aggregate(
    const u16* __restrict__ h, const float* __restrict__ alpha,
    const int* __restrict__ row_st, const int* __restrict__ srcs,
    const float* __restrict__ bias, u16* __restrict__ out)
{
  int n = blockIdx.x, hh = blockIdx.y, tid = threadIdx.x;
  int c0 = hh * 2048 + tid * 8;
  float acc[8];
#pragma unroll
  for (int q = 0; q < 8; ++q) acc[q] = 0.f;
  int b = row_st[n], e = row_st[n + 1];
  for (int p = b; p < e; ++p) {
    int s = srcs[p];
    float a = alpha[p * 4 + hh];
    short8 v = *reinterpret_cast<const short8*>(h + (size_t)s * 8192 + c0);
#pragma unroll
    for (int q = 0; q < 8; ++q) acc[q] += a * bf2f((u16)v[q]);
  }
  short8 ov;
#pragma unroll
  for (int q = 0; q < 8; ++q) ov[q] = (short)f2bf(acc[q] + bias[c0 + q]);
  *reinterpret_cast<short8*>(out + (size_t)n * 8192 + c0) = ov;
}

// ---------------- mean pool over sorted batch --------------------------------
__global__ __launch_bounds__(256) void pool_mean(
    const u16* __restrict__ hf, const int* __restrict__ batch,
    u16* __restrict__ g, int Nn)
{
  int gid = blockIdx.x, tid = threadIdx.x;
  int s1, s2;
  { int l = 0, h = Nn; while (l < h) { int m = (l + h) >> 1; if (batch[m] < gid) l = m + 1; else h = m; } s1 = l; }
  { int l = 0, h = Nn; while (l < h) { int m = (l + h) >> 1; if (batch[m] < gid + 1) l = m + 1; else h = m; } s2 = l; }
  float inv = 1.f / fmaxf((float)(s2 - s1), 1.f);
  float acc[8];
#pragma unroll
  for (int q = 0; q < 8; ++q) acc[q] = 0.f;
  for (int r = s1; r < s2; ++r) {
    short8 v = *reinterpret_cast<const short8*>(hf + (size_t)r * 2048 + tid * 8);
#pragma unroll
    for (int q = 0; q < 8; ++q) acc[q] += bf2f((u16)v[q]);
  }
  short8 ov;
#pragma unroll
  for (int q = 0; q < 8; ++q) ov[q] = (short)f2bf(acc[q] * inv);
  *reinterpret_cast<short8*>(g + (size_t)gid * 2048 + tid * 8) = ov;
}

// ---------------- layernorm over 768 ----------------------------------------
__global__ __launch_bounds__(256) void layernorm_768(
    const float* __restrict__ x, const float* __restrict__ gam,
    const float* __restrict__ bet, float* __restrict__ out)
{
  int row = blockIdx.x, tid = threadIdx.x, lane = tid & 63, w = tid >> 6;
  __shared__ float sh[8];
  float v0 = x[row * 768 + tid];
  float v1 = x[row * 768 + 256 + tid];
  float v2 = x[row * 768 + 512 + tid];
  float s = v0 + v1 + v2;
  for (int off = 32; off; off >>= 1) s += __shfl_down(s, off);
  if (lane == 0) sh[w] = s;
  __syncthreads();
  if (tid == 0) sh[4] = (sh[0] + sh[1] + sh[2] + sh[3]) / 768.f;
  __syncthreads();
  float mu = sh[4];
  float d0 = v0 - mu, d1 = v1 - mu, d2 = v2 - mu;
  float q = d0 * d0 + d1 * d1 + d2 * d2;
  for (int off = 32; off; off >>= 1) q += __shfl_down(q, off);
  if (lane == 0) sh[w] = q;
  __syncthreads();
  if (tid == 0) sh[5] = rsqrtf((sh[0] + sh[1] + sh[2] + sh[3]) / 768.f + 1e-5f);
  __syncthreads();
  float rstd = sh[5];
  out[row * 768 + tid]       = d0 * rstd * gam[tid]       + bet[tid];
  out[row * 768 + 256 + tid] = d1 * rstd * gam[256 + tid] + bet[256 + tid];
  out[row * 768 + 512 + tid] = d2 * rstd * gam[512 + tid] + bet[512 + tid];
}

// ============================================================================
extern "C" void kernel_launch(void* const* d_in, const int* in_sizes, int n_in,
                              void* d_out, int out_size, void* d_ws, size_t ws_size,
                              hipStream_t stream)
{
  const float* x     = (const float*)d_in[0];
  const int*   ei    = (const int*)d_in[1];
  const int*   batch = (const int*)d_in[2];
  const float* W[3]   = {(const float*)d_in[3], (const float*)d_in[9],  (const float*)d_in[15]};
  const float* asr[3] = {(const float*)d_in[4], (const float*)d_in[10], (const float*)d_in[16]};
  const float* ads[3] = {(const float*)d_in[5], (const float*)d_in[11], (const float*)d_in[17]};
  const float* bc[3]  = {(const float*)d_in[6], (const float*)d_in[12], (const float*)d_in[18]};
  const float* Wh[3]  = {(const float*)d_in[7], (const float*)d_in[13], (const float*)d_in[19]};
  const float* bh[3]  = {(const float*)d_in[8], (const float*)d_in[14], (const float*)d_in[20]};
  const float* Wm1 = (const float*)d_in[21];
  const float* bm1 = (const float*)d_in[22];
  const float* Wm2 = (const float*)d_in[23];
  const float* bm2 = (const float*)d_in[24];
  const float* lng = (const float*)d_in[25];
  const float* lnb = (const float*)d_in[26];
  float* out = (float*)d_out;

  int Nn = in_sizes[2];        // 5000
  int E  = in_sizes[1] / 2;    // 15000
  int ET = E + Nn;

  char* base = (char*)d_ws;
  size_t off = 0;
  auto alloc = [&](size_t b) -> char* { char* p = base + off; off = (off + b + 255) & ~(size_t)255; return p; };
  u16*  xb    = (u16*)alloc((size_t)Nn * 320 * 2);
  u16*  Wt    = (u16*)alloc((size_t)8192 * 2048 * 2);
  u16*  Wht   = (u16*)alloc((size_t)8192 * 2048 * 2);
  u16*  hb    = (u16*)alloc((size_t)Nn * 8192 * 2);
  u16*  ob    = (u16*)alloc((size_t)Nn * 8192 * 2);
  u16*  xlb   = (u16*)alloc((size_t)Nn * 2048 * 2);
  float* a_s  = (float*)alloc((size_t)Nn * 4 * 4);
  float* a_d  = (float*)alloc((size_t)Nn * 4 * 4);
  float* alpha= (float*)alloc((size_t)ET * 4 * 4);
  int*  deg   = (int*)alloc((size_t)(Nn + 1) * 4);
  int*  rowst = (int*)alloc((size_t)(Nn + 1) * 4);
  int*  cursor= (int*)alloc((size_t)(Nn + 1) * 4);
  int*  srcs  = (int*)alloc((size_t)ET * 4);
  u16*  g     = (u16*)alloc((size_t)128 * 2048 * 2);
  u16*  g2    = (u16*)alloc((size_t)128 * 2048 * 2);
  float* preln= (float*)alloc((size_t)128 * 768 * 4);

  // ---- CSR by dst (self loops appended) ----
  zero_int<<<(Nn + 255) / 256, 256, 0, stream>>>(deg, Nn);
  count_deg<<<(ET + 255) / 256, 256, 0, stream>>>(ei, E, Nn, deg);
  scan_deg<<<1, 256, 0, stream>>>(deg, rowst, cursor, Nn);
  scatter_edges<<<(ET + 255) / 256, 256, 0, stream>>>(ei, E, Nn, cursor, srcs);

  // ---- input cast (pad K 300->320) ----
  cast_pad<<<(Nn * 320 + 255) / 256, 256, 0, stream>>>(x, xb, Nn, 300, 320);

  const u16* act = xb;
  int mt256 = (Nn + 255) / 256;   // 20
  for (int l = 0; l < 3; ++l) {
    int Kp = (l == 0) ? 320 : 2048;
    transpose_cast<<<dim3(Kp / 32, 8192 / 32), 256, 0, stream>>>(W[l], Wt, (l == 0) ? 300 : 2048, 8192, Kp);
    gemm256<<<dim3(32, mt256), 512, 0, stream>>>(act, Wt, hb, nullptr, Nn, 8192, Kp, 0);
    attn_scores<<<Nn, 256, 0, stream>>>(hb, asr[l], ads[l], a_s, a_d);
    edge_softmax<<<(Nn * 4 + 255) / 256, 256, 0, stream>>>(rowst, srcs, a_s, a_d, alpha, Nn);
    aggregate<<<dim3(Nn, 4), 256, 0, stream>>>(hb, alpha, rowst, srcs, bc[l], ob);
    transpose_cast<<<dim3(8192 / 32, 2048 / 32), 256, 0, stream>>>(Wh[l], Wht, 8192, 2048, 8192);
    gemm256<<<dim3(8, mt256), 512, 0, stream>>>(ob, Wht, xlb, bh[l], Nn, 2048, 8192, (l < 2) ? 1 : 0);
    act = xlb;
  }

  // ---- mean pool + MLP + LN ----
  pool_mean<<<128, 256, 0, stream>>>(xlb, batch, g, Nn);
  transpose_cast<<<dim3(2048 / 32, 2048 / 32), 256, 0, stream>>>(Wm1, Wt, 2048, 2048, 2048);
  gemm_bt<<<dim3(16, 1), 256, 0, stream>>>(g, Wt, nullptr, g2, bm1, 128, 2048, 2048, 1);
  transpose_cast<<<dim3(2048 / 32, 768 / 32), 256, 0, stream>>>(Wm2, Wht, 2048, 768, 2048);
  gemm_bt<<<dim3(6, 1), 256, 0, stream>>>(g2, Wht, preln, nullptr, bm2, 128, 768, 2048, 0);
  layernorm_768<<<128, 256, 0, stream>>>(preln, lng, lnb, out);
}

// Round 6
// 1914.685 us; speedup vs baseline: 1.2263x; 1.0430x over previous
//
#include <hip/hip_runtime.h>

typedef unsigned short u16;
typedef __attribute__((ext_vector_type(8))) short short8;
typedef __attribute__((ext_vector_type(4))) float f32x4;

__device__ inline u16 f2bf(float f){
  unsigned int u = __builtin_bit_cast(unsigned int, f);
  u += 0x7fffu + ((u >> 16) & 1u);
  return (u16)(u >> 16);
}
__device__ inline float bf2f(u16 h){
  unsigned int u = ((unsigned int)h) << 16;
  return __builtin_bit_cast(float, u);
}

typedef __attribute__((address_space(1))) const void* as1_t;
typedef __attribute__((address_space(3))) void* as3_t;
__device__ __forceinline__ void gload16(const u16* g, u16* l) {
  __builtin_amdgcn_global_load_lds((as1_t)g, (as3_t)l, 16, 0, 0);
}

#define BARRIER() asm volatile("s_barrier" ::: "memory")
#define VMCNT2()  asm volatile("s_waitcnt vmcnt(2)" ::: "memory")
#define VMCNT4()  asm volatile("s_waitcnt vmcnt(4)" ::: "memory")
#define VMCNT0()  asm volatile("s_waitcnt vmcnt(0)" ::: "memory")
// XOR swizzle within a 16KB [256 row][64 B] operand tile: byte bits 4-5 ^=
// (row&3)^((row>>2)&3). Involution, 16B-chunk-preserving. Read pattern
// (16 rows x 4 k-slots) lands 2 lanes/16B-slot = free (m136).
__device__ __forceinline__ int swz(int b) {
  return b ^ ((b >> 2) & 0x30) ^ ((b >> 4) & 0x30);
}

// ---------------- weight transpose + cast:  W[K,N] f32 -> Wt[N,Kpad] bf16 ----
__global__ __launch_bounds__(256) void transpose_cast(
    const float* __restrict__ W, u16* __restrict__ Wt, int K, int N, int Kpad)
{
  __shared__ float tile[32][33];
  int k0 = blockIdx.x * 32, n0 = blockIdx.y * 32;
  int tx = threadIdx.x & 31, ty = threadIdx.x >> 5;
#pragma unroll
  for (int i = 0; i < 4; ++i) {
    int k = k0 + ty + i * 8;
    float v = 0.f;
    if (k < K && (n0 + tx) < N) v = W[(size_t)k * N + n0 + tx];
    tile[ty + i * 8][tx] = v;
  }
  __syncthreads();
#pragma unroll
  for (int i = 0; i < 4; ++i) {
    int nn = n0 + ty + i * 8;
    if (nn < N) Wt[(size_t)nn * Kpad + k0 + tx] = f2bf(tile[tx][ty + i * 8]);
  }
}

// ---------------- x cast with K padding -------------------------------------
__global__ void cast_pad(const float* __restrict__ x, u16* __restrict__ xb,
                         int R, int C, int Cp)
{
  int i = blockIdx.x * 256 + threadIdx.x;
  if (i >= R * Cp) return;
  int r = i / Cp, c = i % Cp;
  xb[i] = f2bf(c < C ? x[(size_t)r * C + c] : 0.f);
}

// ================= 256x256 pipelined GEMM, reg-double-buffered frags =========
// C[M,N] = A[M,K] @ B[N,K]^T. K%64==0 or K%32==0 with NT even (K in
// {320,2048,8192} -> NT in {10,64,256}, all even). N%256==0. 512 thr = 8 waves
// (2Mx4N), per-wave 128x64. BK=32, 3 LDS buffers, prefetch distance 2.
// Schedule per iter t (tile t's frags already in registers):
//   h0: stage 2 gloads (tile t+2) | MFMA mh=0 | vmcnt(2) | barrier
//       (barrier gates tile t+1 LDS-residency for ALL waves)
//   h1: ds_read all 12 frags of tile t+1 | stage 2 gloads | MFMA mh=1
//       (reads overlap the MFMAs; consumed next iter)
// WAR ledger for buffer (t+2)%3 (holds tile t-1): last reads of tile t-1 were
// issued at iter t-2 h1 and consumed (lgkm-waited) by each wave before its
// iter t-1 MFMAs; the overwriting gloads issue at iter t h0, >= one full
// MFMA-half later + >=200cy DMA latency. Safe.
__global__ __launch_bounds__(512, 2) void gemm256(
    const u16* __restrict__ A, const u16* __restrict__ B,
    u16* __restrict__ C, const float* __restrict__ bias,
    int M, int N, int K, int relu)
{
  __shared__ alignas(16) u16 lds[3 * 16384];   // 3 bufs x (A 16KB | B 16KB)
  int tid = threadIdx.x;
  int wave = tid >> 6, lane = tid & 63;
  int wm = wave >> 2, wn = wave & 3;
  int tile_m = blockIdx.y * 256, tile_n = blockIdx.x * 256;
  int NT = K >> 5;

  // ---- stage sources: LDS dest linear, global source pre-swizzled ----
  const u16* src[4];
  int ubase[4];
#pragma unroll
  for (int j = 0; j < 4; ++j) {
    int op = j >> 1, sw = j & 1;
    int L  = sw * 8192 + tid * 16;
    int Ls = swz(L);
    int grow = Ls >> 6;
    int gcol = (Ls & 63) >> 1;
    src[j] = (op ? B + (size_t)(tile_n + grow) * K
                 : A + (size_t)(tile_m + grow) * K) + gcol;
    ubase[j] = op * 8192 + sw * 4096 + wave * 512;
  }

  // ---- fragment read offsets (u16 index within a 32KB buffer) ----
  int l15 = lane & 15, k16 = lane >> 4;
  int aoff[2][4], boff[4];
#pragma unroll
  for (int mh = 0; mh < 2; ++mh)
#pragma unroll
    for (int mi = 0; mi < 4; ++mi) {
      int row = wm * 128 + mh * 64 + mi * 16 + l15;
      aoff[mh][mi] = swz(row * 64 + k16 * 16) >> 1;
    }
#pragma unroll
  for (int ni = 0; ni < 4; ++ni) {
    int row = wn * 64 + ni * 16 + l15;
    boff[ni] = 8192 + (swz(row * 64 + k16 * 16) >> 1);
  }

  f32x4 acc[2][4][4];
#pragma unroll
  for (int mh = 0; mh < 2; ++mh)
#pragma unroll
    for (int mi = 0; mi < 4; ++mi)
#pragma unroll
      for (int ni = 0; ni < 4; ++ni) { f32x4 z = {0.f,0.f,0.f,0.f}; acc[mh][mi][ni] = z; }

#define LDSET_A(dst, base, mh) \
  _Pragma("unroll") for (int mi = 0; mi < 4; ++mi) \
    dst[mi] = *reinterpret_cast<const short8*>(&lds[(base) + aoff[mh][mi]]);
#define LDSET_B(dst, base) \
  _Pragma("unroll") for (int ni = 0; ni < 4; ++ni) \
    dst[ni] = *reinterpret_cast<const short8*>(&lds[(base) + boff[ni]]);
#define MFMA_HALF(mh, fa, fb) \
  _Pragma("unroll") for (int mi = 0; mi < 4; ++mi) \
  _Pragma("unroll") for (int ni = 0; ni < 4; ++ni) \
    acc[mh][mi][ni] = __builtin_amdgcn_mfma_f32_16x16x32_bf16(fa[mi], fb[ni], acc[mh][mi][ni], 0, 0, 0);

  short8 fa0[4], fa1a[4], fa1b[4], fba[4], fbb[4];

  // ---- prologue: stage tiles 0 (buf0) and 1 (buf1) ----
#pragma unroll
  for (int j = 0; j < 4; ++j) gload16(src[j], &lds[ubase[j]]);
#pragma unroll
  for (int j = 0; j < 4; ++j) gload16(src[j] + 32, &lds[16384 + ubase[j]]);
  VMCNT4();          // tile 0 resident (own); tile 1 in flight
  BARRIER();         // all waves' tile-0 loads done
  LDSET_A(fa0, 0, 0);
  LDSET_A(fa1a, 0, 1);
  LDSET_B(fba, 0);

#define GITER(t, FA1C, FA1N, FBC, FBN) { \
    int nb  = (((t) + 2) % 3) * 16384; \
    int nb1 = (((t) + 1) % 3) * 16384; \
    bool st = (t) + 2 < NT; \
    int kadv = ((t) + 2) * 32; \
    /* ---- half 0 ---- */ \
    if (st) { gload16(src[0] + kadv, &lds[nb + ubase[0]]); \
              gload16(src[1] + kadv, &lds[nb + ubase[1]]); } \
    MFMA_HALF(0, fa0, FBC); \
    if (st) { VMCNT2(); } else { VMCNT0(); } \
    BARRIER(); \
    /* ---- half 1: read next tile's frags, overlap with MFMA ---- */ \
    if ((t) + 1 < NT) { \
      LDSET_A(fa0, nb1, 0); \
      LDSET_A(FA1N, nb1, 1); \
      LDSET_B(FBN, nb1); \
      __builtin_amdgcn_sched_barrier(0); \
    } \
    if (st) { gload16(src[2] + kadv, &lds[nb + ubase[2]]); \
              gload16(src[3] + kadv, &lds[nb + ubase[3]]); } \
    MFMA_HALF(1, FA1C, FBC); \
  }

  for (int t = 0; t < NT; t += 2) {
    GITER(t,     fa1a, fa1b, fba, fbb);
    GITER(t + 1, fa1b, fa1a, fbb, fba);
  }

  // ---- epilogue: direct bf16 stores (C/D map: col=lane&15, row=(lane>>4)*4+j)
  int rq = (lane >> 4) * 4;
#pragma unroll
  for (int mh = 0; mh < 2; ++mh)
#pragma unroll
    for (int mi = 0; mi < 4; ++mi)
#pragma unroll
      for (int ni = 0; ni < 4; ++ni) {
        int col = tile_n + wn * 64 + ni * 16 + l15;
        float bv = bias ? bias[col] : 0.f;
#pragma unroll
        for (int j = 0; j < 4; ++j) {
          int row = tile_m + wm * 128 + mh * 64 + mi * 16 + rq + j;
          if (row < M) {
            float v = acc[mh][mi][ni][j] + bv;
            if (relu) v = fmaxf(v, 0.f);
            C[(size_t)row * N + col] = f2bf(v);
          }
        }
      }
#undef GITER
#undef LDSET_A
#undef LDSET_B
#undef MFMA_HALF
}

// ---------------- 128x128 GEMM (R2 structure, small/f32 cases) ---------------
__global__ __launch_bounds__(256) void gemm_bt(
    const u16* __restrict__ A, const u16* __restrict__ B,
    float* __restrict__ Cf, u16* __restrict__ Cb,
    const float* __restrict__ bias, int M, int N, int K, int relu)
{
  __shared__ alignas(16) u16 As[128 * 32];
  __shared__ alignas(16) u16 Bs[128 * 32];
  int tid = threadIdx.x;
  int wave = tid >> 6, lane = tid & 63;
  int wr = wave >> 1, wc = wave & 1;
  int tile_m = blockIdx.y * 128, tile_n = blockIdx.x * 128;

  int sr = wave * 16 + (lane >> 2);
  int sc = (lane & 3) * 8;
  const u16* gA0 = A + (size_t)(tile_m + sr) * K + sc;
  const u16* gA1 = A + (size_t)(tile_m + 64 + sr) * K + sc;
  const u16* gB0 = B + (size_t)(tile_n + sr) * K + sc;
  const u16* gB1 = B + (size_t)(tile_n + 64 + sr) * K + sc;
  u16* lA0 = &As[wave * 512];
  u16* lA1 = &As[2048 + wave * 512];
  u16* lB0 = &Bs[wave * 512];
  u16* lB1 = &Bs[2048 + wave * 512];

  f32x4 acc[4][4];
#pragma unroll
  for (int mi = 0; mi < 4; ++mi)
#pragma unroll
    for (int ni = 0; ni < 4; ++ni) { f32x4 z = {0.f,0.f,0.f,0.f}; acc[mi][ni] = z; }

  int lrow = lane & 15, lk = (lane >> 4) * 8;

  for (int k0 = 0; k0 < K; k0 += 32) {
    gload16(gA0 + k0, lA0);
    gload16(gA1 + k0, lA1);
    gload16(gB0 + k0, lB0);
    gload16(gB1 + k0, lB1);
    __syncthreads();
    short8 af[4], bfr[4];
#pragma unroll
    for (int mi = 0; mi < 4; ++mi)
      af[mi] = *reinterpret_cast<const short8*>(&As[(wr * 64 + mi * 16 + lrow) * 32 + lk]);
#pragma unroll
    for (int ni = 0; ni < 4; ++ni)
      bfr[ni] = *reinterpret_cast<const short8*>(&Bs[(wc * 64 + ni * 16 + lrow) * 32 + lk]);
#pragma unroll
    for (int mi = 0; mi < 4; ++mi)
#pragma unroll
      for (int ni = 0; ni < 4; ++ni)
        acc[mi][ni] = __builtin_amdgcn_mfma_f32_16x16x32_bf16(af[mi], bfr[ni], acc[mi][ni], 0, 0, 0);
    __syncthreads();
  }

  int rquad = (lane >> 4) * 4;
#pragma unroll
  for (int mi = 0; mi < 4; ++mi)
#pragma unroll
    for (int ni = 0; ni < 4; ++ni) {
      int col = tile_n + wc * 64 + ni * 16 + lrow;
      float bv = bias ? bias[col] : 0.f;
#pragma unroll
      for (int j = 0; j < 4; ++j) {
        int row = tile_m + wr * 64 + mi * 16 + rquad + j;
        if (row < M) {
          float v = acc[mi][ni][j] + bv;
          if (relu) v = fmaxf(v, 0.f);
          if (Cb) Cb[(size_t)row * N + col] = f2bf(v);
          else    Cf[(size_t)row * N + col] = v;
        }
      }
    }
}

// ---------------- attention scores: a_src/a_dst [N,4] -----------------------
__global__ __launch_bounds__(256) void attn_scores(
    const u16* __restrict__ h, const float* __restrict__ asrc,
    const float* __restrict__ adst, float* __restrict__ a_s, float* __restrict__ a_d)
{
  int n = blockIdx.x;
  int hh = threadIdx.x >> 6, lane = threadIdx.x & 63;
  const u16* hr = h + (size_t)n * 8192 + hh * 2048;
  const float* as = asrc + hh * 2048;
  const float* ad = adst + hh * 2048;
  float ssum = 0.f, dsum = 0.f;
#pragma unroll
  for (int i = 0; i < 4; ++i) {
    int c = lane * 8 + i * 512;
    short8 v = *reinterpret_cast<const short8*>(hr + c);
#pragma unroll
    for (int j = 0; j < 8; ++j) {
      float f = bf2f((u16)v[j]);
      ssum += f * as[c + j];
      dsum += f * ad[c + j];
    }
  }
  for (int off = 32; off; off >>= 1) {
    ssum += __shfl_down(ssum, off);
    dsum += __shfl_down(dsum, off);
  }
  if (lane == 0) { a_s[n * 4 + hh] = ssum; a_d[n * 4 + hh] = dsum; }
}

// ---------------- CSR build --------------------------------------------------
__global__ void zero_int(int* p, int n){ int i = blockIdx.x*256+threadIdx.x; if (i < n) p[i] = 0; }

__global__ void count_deg(const int* __restrict__ ei, int E, int Nn, int* __restrict__ deg){
  int e = blockIdx.x*256+threadIdx.x; if (e >= E + Nn) return;
  int d = (e < E) ? ei[E + e] : (e - E);
  atomicAdd(&deg[d], 1);
}

__global__ void scan_deg(const int* __restrict__ deg, int* __restrict__ row_st,
                         int* __restrict__ cursor, int Nn){
  __shared__ int partial[256];
  int tid = threadIdx.x;
  int chunk = (Nn + 255) / 256;
  int start = tid * chunk;
  int sum = 0;
  for (int i = 0; i < chunk; ++i) { int idx = start + i; if (idx < Nn) sum += deg[idx]; }
  partial[tid] = sum;
  __syncthreads();
  if (tid == 0) { int acc = 0; for (int i = 0; i < 256; ++i) { int t = partial[i]; partial[i] = acc; acc += t; } }
  __syncthreads();
  int acc = partial[tid];
  for (int i = 0; i < chunk; ++i) {
    int idx = start + i;
    if (idx < Nn) { row_st[idx] = acc; cursor[idx] = acc; acc += deg[idx]; }
  }
  if (tid == 255) row_st[Nn] = acc;
}

__global__ void scatter_edges(const int* __restrict__ ei, int E, int Nn,
                              int* __restrict__ cursor, int* __restrict__ srcs){
  int e = blockIdx.x*256+threadIdx.x; if (e >= E + Nn) return;
  int s = (e < E) ? ei[e]     : (e - E);
  int d = (e < E) ? ei[E + e] : (e - E);
  int pos = atomicAdd(&cursor[d], 1);
  srcs[pos] = s;
}

// ---------------- per-(node,head) edge softmax -------------------------------
__global__ void edge_softmax(const int* __restrict__ row_st, const int* __restrict__ srcs,
                             const float* __restrict__ a_s, const float* __restrict__ a_d,
                             float* __restrict__ alpha, int Nn){
  int t = blockIdx.x*256+threadIdx.x;
  if (t >= Nn * 4) return;
  int n = t >> 2, hh = t & 3;
  int b = row_st[n], e = row_st[n + 1];
  float ad = a_d[n * 4 + hh];
  float m = -1e30f;
  for (int p = b; p < e; ++p) {
    float x = a_s[srcs[p] * 4 + hh] + ad;
    x = x > 0.f ? x : 0.2f * x;
    alpha[p * 4 + hh] = x;
    m = fmaxf(m, x);
  }
  float ssum = 0.f;
  for (int p = b; p < e; ++p) {
    float ex = expf(alpha[p * 4 + hh] - m);
    alpha[p * 4 + hh] = ex;
    ssum += ex;
  }
  float inv = 1.f / (ssum + 1e-16f);
  for (int p = b; p < e; ++p) alpha[p * 4 + hh] *= inv;
}

// ---------------- aggregation: out[n, hh*2048:] = sum alpha*h[src] + bias ----
__global__ __launch_bounds__(256) void aggregate(
    const u16* __restrict__ h, const float* __restrict__ alpha,
    const int* __restrict__ row_st, const int* __restrict__ srcs,
    const float* __restrict__ bias, u16* __restrict__ out)
{
  int n = blockIdx.x, hh = blockIdx.y, tid = threadIdx.x;
  int c0 = hh * 2048 + tid * 8;
  float acc[8];
#pragma unroll
  for (int q = 0; q < 8; ++q) acc[q] = 0.f;
  int b = row_st[n], e = row_st[n + 1];
  for (int p = b; p < e; ++p) {
    int s = srcs[p];
    float a = alpha[p * 4 + hh];
    short8 v = *reinterpret_cast<const short8*>(h + (size_t)s * 8192 + c0);
#pragma unroll
    for (int q = 0; q < 8; ++q) acc[q] += a * bf2f((u16)v[q]);
  }
  short8 ov;
#pragma unroll
  for (int q = 0; q < 8; ++q) ov[q] = (short)f2bf(acc[q] + bias[c0 + q]);
  *reinterpret_cast<short8*>(out + (size_t)n * 8192 + c0) = ov;
}

// ---------------- mean pool over sorted batch --------------------------------
__global__ __launch_bounds__(256) void pool_mean(
    const u16* __restrict__ hf, const int* __restrict__ batch,
    u16* __restrict__ g, int Nn)
{
  int gid = blockIdx.x, tid = threadIdx.x;
  int s1, s2;
  { int l = 0, h = Nn; while (l < h) { int m = (l + h) >> 1; if (batch[m] < gid) l = m + 1; else h = m; } s1 = l; }
  { int l = 0, h = Nn; while (l < h) { int m = (l + h) >> 1; if (batch[m] < gid + 1) l = m + 1; else h = m; } s2 = l; }
  float inv = 1.f / fmaxf((float)(s2 - s1), 1.f);
  float acc[8];
#pragma unroll
  for (int q = 0; q < 8; ++q) acc[q] = 0.f;
  for (int r = s1; r < s2; ++r) {
    short8 v = *reinterpret_cast<const short8*>(hf + (size_t)r * 2048 + tid * 8);
#pragma unroll
    for (int q = 0; q < 8; ++q) acc[q] += bf2f((u16)v[q]);
  }
  short8 ov;
#pragma unroll
  for (int q = 0; q < 8; ++q) ov[q] = (short)f2bf(acc[q] * inv);
  *reinterpret_cast<short8*>(g + (size_t)gid * 2048 + tid * 8) = ov;
}

// ---------------- layernorm over 768 ----------------------------------------
__global__ __launch_bounds__(256) void layernorm_768(
    const float* __restrict__ x, const float* __restrict__ gam,
    const float* __restrict__ bet, float* __restrict__ out)
{
  int row = blockIdx.x, tid = threadIdx.x, lane = tid & 63, w = tid >> 6;
  __shared__ float sh[8];
  float v0 = x[row * 768 + tid];
  float v1 = x[row * 768 + 256 + tid];
  float v2 = x[row * 768 + 512 + tid];
  float s = v0 + v1 + v2;
  for (int off = 32; off; off >>= 1) s += __shfl_down(s, off);
  if (lane == 0) sh[w] = s;
  __syncthreads();
  if (tid == 0) sh[4] = (sh[0] + sh[1] + sh[2] + sh[3]) / 768.f;
  __syncthreads();
  float mu = sh[4];
  float d0 = v0 - mu, d1 = v1 - mu, d2 = v2 - mu;
  float q = d0 * d0 + d1 * d1 + d2 * d2;
  for (int off = 32; off; off >>= 1) q += __shfl_down(q, off);
  if (lane == 0) sh[w] = q;
  __syncthreads();
  if (tid == 0) sh[5] = rsqrtf((sh[0] + sh[1] + sh[2] + sh[3]) / 768.f + 1e-5f);
  __syncthreads();
  float rstd = sh[5];
  out[row * 768 + tid]       = d0 * rstd * gam[tid]       + bet[tid];
  out[row * 768 + 256 + tid] = d1 * rstd * gam[256 + tid] + bet[256 + tid];
  out[row * 768 + 512 + tid] = d2 * rstd * gam[512 + tid] + bet[512 + tid];
}

// ============================================================================
extern "C" void kernel_launch(void* const* d_in, const int* in_sizes, int n_in,
                              void* d_out, int out_size, void* d_ws, size_t ws_size,
                              hipStream_t stream)
{
  const float* x     = (const float*)d_in[0];
  const int*   ei    = (const int*)d_in[1];
  const int*   batch = (const int*)d_in[2];
  const float* W[3]   = {(const float*)d_in[3], (const float*)d_in[9],  (const float*)d_in[15]};
  const float* asr[3] = {(const float*)d_in[4], (const float*)d_in[10], (const float*)d_in[16]};
  const float* ads[3] = {(const float*)d_in[5], (const float*)d_in[11], (const float*)d_in[17]};
  const float* bc[3]  = {(const float*)d_in[6], (const float*)d_in[12], (const float*)d_in[18]};
  const float* Wh[3]  = {(const float*)d_in[7], (const float*)d_in[13], (const float*)d_in[19]};
  const float* bh[3]  = {(const float*)d_in[8], (const float*)d_in[14], (const float*)d_in[20]};
  const float* Wm1 = (const float*)d_in[21];
  const float* bm1 = (const float*)d_in[22];
  const float* Wm2 = (const float*)d_in[23];
  const float* bm2 = (const float*)d_in[24];
  const float* lng = (const float*)d_in[25];
  const float* lnb = (const float*)d_in[26];
  float* out = (float*)d_out;

  int Nn = in_sizes[2];        // 5000
  int E  = in_sizes[1] / 2;    // 15000
  int ET = E + Nn;

  char* base = (char*)d_ws;
  size_t off = 0;
  auto alloc = [&](size_t b) -> char* { char* p = base + off; off = (off + b + 255) & ~(size_t)255; return p; };
  u16*  xb    = (u16*)alloc((size_t)Nn * 320 * 2);
  u16*  Wt    = (u16*)alloc((size_t)8192 * 2048 * 2);
  u16*  Wht   = (u16*)alloc((size_t)8192 * 2048 * 2);
  u16*  hb    = (u16*)alloc((size_t)Nn * 8192 * 2);
  u16*  ob    = (u16*)alloc((size_t)Nn * 8192 * 2);
  u16*  xlb   = (u16*)alloc((size_t)Nn * 2048 * 2);
  float* a_s  = (float*)alloc((size_t)Nn * 4 * 4);
  float* a_d  = (float*)alloc((size_t)Nn * 4 * 4);
  float* alpha= (float*)alloc((size_t)ET * 4 * 4);
  int*  deg   = (int*)alloc((size_t)(Nn + 1) * 4);
  int*  rowst = (int*)alloc((size_t)(Nn + 1) * 4);
  int*  cursor= (int*)alloc((size_t)(Nn + 1) * 4);
  int*  srcs  = (int*)alloc((size_t)ET * 4);
  u16*  g     = (u16*)alloc((size_t)128 * 2048 * 2);
  u16*  g2    = (u16*)alloc((size_t)128 * 2048 * 2);
  float* preln= (float*)alloc((size_t)128 * 768 * 4);

  // ---- CSR by dst (self loops appended) ----
  zero_int<<<(Nn + 255) / 256, 256, 0, stream>>>(deg, Nn);
  count_deg<<<(ET + 255) / 256, 256, 0, stream>>>(ei, E, Nn, deg);
  scan_deg<<<1, 256, 0, stream>>>(deg, rowst, cursor, Nn);
  scatter_edges<<<(ET + 255) / 256, 256, 0, stream>>>(ei, E, Nn, cursor, srcs);

  // ---- input cast (pad K 300->320) ----
  cast_pad<<<(Nn * 320 + 255) / 256, 256, 0, stream>>>(x, xb, Nn, 300, 320);

  const u16* act = xb;
  int mt256 = (Nn + 255) / 256;   // 20
  for (int l = 0; l < 3; ++l) {
    int Kp = (l == 0) ? 320 : 2048;
    transpose_cast<<<dim3(Kp / 32, 8192 / 32), 256, 0, stream>>>(W[l], Wt, (l == 0) ? 300 : 2048, 8192, Kp);
    gemm256<<<dim3(32, mt256), 512, 0, stream>>>(act, Wt, hb, nullptr, Nn, 8192, Kp, 0);
    attn_scores<<<Nn, 256, 0, stream>>>(hb, asr[l], ads[l], a_s, a_d);
    edge_softmax<<<(Nn * 4 + 255) / 256, 256, 0, stream>>>(rowst, srcs, a_s, a_d, alpha, Nn);
    aggregate<<<dim3(Nn, 4), 256, 0, stream>>>(hb, alpha, rowst, srcs, bc[l], ob);
    transpose_cast<<<dim3(8192 / 32, 2048 / 32), 256, 0, stream>>>(Wh[l], Wht, 8192, 2048, 8192);
    gemm256<<<dim3(8, mt256), 512, 0, stream>>>(ob, Wht, xlb, bh[l], Nn, 2048, 8192, (l < 2) ? 1 : 0);
    act = xlb;
  }

  // ---- mean pool + MLP + LN ----
  pool_mean<<<128, 256, 0, stream>>>(xlb, batch, g, Nn);
  transpose_cast<<<dim3(2048 / 32, 2048 / 32), 256, 0, stream>>>(Wm1, Wt, 2048, 2048, 2048);
  gemm_bt<<<dim3(16, 1), 256, 0, stream>>>(g, Wt, nullptr, g2, bm1, 128, 2048, 2048, 1);
  transpose_cast<<<dim3(2048 / 32, 768 / 32), 256, 0, stream>>>(Wm2, Wht, 2048, 768, 2048);
  gemm_bt<<<dim3(6, 1), 256, 0, stream>>>(g2, Wht, preln, nullptr, bm2, 128, 768, 2048, 0);
  layernorm_768<<<128, 256, 0, stream>>>(preln, lng, lnb, out);
}

// Round 7
// 1839.717 us; speedup vs baseline: 1.2763x; 1.0408x over previous
//
#include <hip/hip_runtime.h>

typedef unsigned short u16;
typedef __attribute__((ext_vector_type(8))) short short8;
typedef __attribute__((ext_vector_type(4))) float f32x4;

__device__ inline u16 f2bf(float f){
  unsigned int u = __builtin_bit_cast(unsigned int, f);
  u += 0x7fffu + ((u >> 16) & 1u);
  return (u16)(u >> 16);
}
__device__ inline float bf2f(u16 h){
  unsigned int u = ((unsigned int)h) << 16;
  return __builtin_bit_cast(float, u);
}

typedef __attribute__((address_space(1))) const void* as1_t;
typedef __attribute__((address_space(3))) void* as3_t;
__device__ __forceinline__ void gload16(const u16* g, u16* l) {
  __builtin_amdgcn_global_load_lds((as1_t)g, (as3_t)l, 16, 0, 0);
}

#define BARRIER() asm volatile("s_barrier" ::: "memory")
#define VMCNT8()  asm volatile("s_waitcnt vmcnt(8)" ::: "memory")
#define VMCNT6()  asm volatile("s_waitcnt vmcnt(6)" ::: "memory")
#define VMCNT4()  asm volatile("s_waitcnt vmcnt(4)" ::: "memory")
#define VMCNT0()  asm volatile("s_waitcnt vmcnt(0)" ::: "memory")
// XOR swizzle: byte bits 4-5 ^= (row&3)^((row>>2)&3). Involution, keeps 16B
// chunks contiguous; read pattern (16 rows x 4 k-slots) -> 2 lanes/slot = free.
__device__ __forceinline__ int swz(int b) {
  return b ^ ((b >> 2) & 0x30) ^ ((b >> 4) & 0x30);
}

// ---------------- weight transpose + cast:  W[K,N] f32 -> Wt[N,Kpad] bf16 ----
__global__ __launch_bounds__(256) void transpose_cast(
    const float* __restrict__ W, u16* __restrict__ Wt, int K, int N, int Kpad)
{
  __shared__ float tile[32][33];
  int k0 = blockIdx.x * 32, n0 = blockIdx.y * 32;
  int tx = threadIdx.x & 31, ty = threadIdx.x >> 5;
#pragma unroll
  for (int i = 0; i < 4; ++i) {
    int k = k0 + ty + i * 8;
    float v = 0.f;
    if (k < K && (n0 + tx) < N) v = W[(size_t)k * N + n0 + tx];
    tile[ty + i * 8][tx] = v;
  }
  __syncthreads();
#pragma unroll
  for (int i = 0; i < 4; ++i) {
    int nn = n0 + ty + i * 8;
    if (nn < N) Wt[(size_t)nn * Kpad + k0 + tx] = f2bf(tile[tx][ty + i * 8]);
  }
}

// ---------------- x cast with K padding -------------------------------------
__global__ void cast_pad(const float* __restrict__ x, u16* __restrict__ xb,
                         int R, int C, int Cp)
{
  int i = blockIdx.x * 256 + threadIdx.x;
  if (i >= R * Cp) return;
  int r = i / Cp, c = i % Cp;
  xb[i] = f2bf(c < C ? x[(size_t)r * C + c] : 0.f);
}

// ================= 256x256 pipelined GEMM, prefetch-3, 4 LDS bufs ============
// C[M,N] = A[M,K] @ B[N,K]^T. NT=K/32 even. N%256==0. 512 thr = 8 waves (2Mx4N).
// WAR ledger (4 bufs, distance 3): buf[(t+3)%4] holds tile t-1; its frag-reads
// (issued iter t-2 h1) are lgkm-consumed before iter t-1 h0 MFMAs, which all
// waves complete before the iter t-1 h0 barrier; overwriting gloads issue at
// iter t h0, after that barrier. Safe.
__global__ __launch_bounds__(512, 2) void gemm256(
    const u16* __restrict__ A, const u16* __restrict__ B,
    u16* __restrict__ C, const float* __restrict__ bias,
    int M, int N, int K, int relu)
{
  __shared__ alignas(16) u16 lds[4 * 16384];   // 4 bufs x (A 16KB | B 16KB)
  int tid = threadIdx.x;
  int wave = tid >> 6, lane = tid & 63;
  int wm = wave >> 2, wn = wave & 3;
  int tile_m = blockIdx.y * 256, tile_n = blockIdx.x * 256;
  int NT = K >> 5;

  const u16* src[4];
  int ubase[4];
#pragma unroll
  for (int j = 0; j < 4; ++j) {
    int op = j >> 1, sw = j & 1;
    int L  = sw * 8192 + tid * 16;
    int Ls = swz(L);
    int grow = Ls >> 6;
    int gcol = (Ls & 63) >> 1;
    src[j] = (op ? B + (size_t)(tile_n + grow) * K
                 : A + (size_t)(tile_m + grow) * K) + gcol;
    ubase[j] = op * 8192 + sw * 4096 + wave * 512;
  }

  int l15 = lane & 15, k16 = lane >> 4;
  int aoff[2][4], boff[4];
#pragma unroll
  for (int mh = 0; mh < 2; ++mh)
#pragma unroll
    for (int mi = 0; mi < 4; ++mi) {
      int row = wm * 128 + mh * 64 + mi * 16 + l15;
      aoff[mh][mi] = swz(row * 64 + k16 * 16) >> 1;
    }
#pragma unroll
  for (int ni = 0; ni < 4; ++ni) {
    int row = wn * 64 + ni * 16 + l15;
    boff[ni] = 8192 + (swz(row * 64 + k16 * 16) >> 1);
  }

  f32x4 acc[2][4][4];
#pragma unroll
  for (int mh = 0; mh < 2; ++mh)
#pragma unroll
    for (int mi = 0; mi < 4; ++mi)
#pragma unroll
      for (int ni = 0; ni < 4; ++ni) { f32x4 z = {0.f,0.f,0.f,0.f}; acc[mh][mi][ni] = z; }

#define LDSET_A(dst, base, mh) \
  _Pragma("unroll") for (int mi = 0; mi < 4; ++mi) \
    dst[mi] = *reinterpret_cast<const short8*>(&lds[(base) + aoff[mh][mi]]);
#define LDSET_B(dst, base) \
  _Pragma("unroll") for (int ni = 0; ni < 4; ++ni) \
    dst[ni] = *reinterpret_cast<const short8*>(&lds[(base) + boff[ni]]);
#define MFMA_HALF(mh, fa, fb) \
  _Pragma("unroll") for (int mi = 0; mi < 4; ++mi) \
  _Pragma("unroll") for (int ni = 0; ni < 4; ++ni) \
    acc[mh][mi][ni] = __builtin_amdgcn_mfma_f32_16x16x32_bf16(fa[mi], fb[ni], acc[mh][mi][ni], 0, 0, 0);

  short8 fa0[4], fa1a[4], fa1b[4], fba[4], fbb[4];

  // prologue: stage tiles 0,1,2 into bufs 0,1,2
#pragma unroll
  for (int j = 0; j < 4; ++j) gload16(src[j], &lds[ubase[j]]);
#pragma unroll
  for (int j = 0; j < 4; ++j) gload16(src[j] + 32, &lds[16384 + ubase[j]]);
#pragma unroll
  for (int j = 0; j < 4; ++j) gload16(src[j] + 64, &lds[32768 + ubase[j]]);
  VMCNT8();
  BARRIER();
  LDSET_A(fa0, 0, 0);
  LDSET_A(fa1a, 0, 1);
  LDSET_B(fba, 0);

#define GITER(t, FA1C, FA1N, FBC, FBN) { \
    int nb  = (((t) + 3) & 3) * 16384; \
    int nb1 = (((t) + 1) & 3) * 16384; \
    bool st = (t) + 3 < NT; \
    int kadv = ((t) + 3) * 32; \
    if (st) { gload16(src[0] + kadv, &lds[nb + ubase[0]]); \
              gload16(src[1] + kadv, &lds[nb + ubase[1]]); } \
    MFMA_HALF(0, fa0, FBC); \
    if (st) { VMCNT6(); } else if ((t) + 2 < NT) { VMCNT4(); } else { VMCNT0(); } \
    BARRIER(); \
    if ((t) + 1 < NT) { \
      LDSET_A(fa0, nb1, 0); \
      LDSET_A(FA1N, nb1, 1); \
      LDSET_B(FBN, nb1); \
      __builtin_amdgcn_sched_barrier(0); \
    } \
    if (st) { gload16(src[2] + kadv, &lds[nb + ubase[2]]); \
              gload16(src[3] + kadv, &lds[nb + ubase[3]]); } \
    MFMA_HALF(1, FA1C, FBC); \
  }

  for (int t = 0; t < NT; t += 2) {
    GITER(t,     fa1a, fa1b, fba, fbb);
    GITER(t + 1, fa1b, fa1a, fbb, fba);
  }

  int rq = (lane >> 4) * 4;
#pragma unroll
  for (int mh = 0; mh < 2; ++mh)
#pragma unroll
    for (int mi = 0; mi < 4; ++mi)
#pragma unroll
      for (int ni = 0; ni < 4; ++ni) {
        int col = tile_n + wn * 64 + ni * 16 + l15;
        float bv = bias ? bias[col] : 0.f;
#pragma unroll
        for (int j = 0; j < 4; ++j) {
          int row = tile_m + wm * 128 + mh * 64 + mi * 16 + rq + j;
          if (row < M) {
            float v = acc[mh][mi][ni][j] + bv;
            if (relu) v = fmaxf(v, 0.f);
            C[(size_t)row * N + col] = f2bf(v);
          }
        }
      }
#undef GITER
#undef LDSET_A
#undef LDSET_B
#undef MFMA_HALF
}

// ================= 128x128 pipelined GEMM, prefetch-3, 4 LDS bufs ============
// Same schedule at 128^2: 256 thr = 4 waves (2x2), per-wave 64x64, 64KB LDS
// -> 2 blocks/CU co-resident (sibling fills vmcnt stalls). NT even.
__global__ __launch_bounds__(256, 2) void gemm128p(
    const u16* __restrict__ A, const u16* __restrict__ B,
    u16* __restrict__ C, const float* __restrict__ bias,
    int M, int N, int K, int relu)
{
  __shared__ alignas(16) u16 lds[4 * 8192];   // 4 bufs x (A 8KB | B 8KB)
  int tid = threadIdx.x;
  int wave = tid >> 6, lane = tid & 63;
  int wr = wave >> 1, wc = wave & 1;
  int tile_m = blockIdx.y * 128, tile_n = blockIdx.x * 128;
  int NT = K >> 5;

  const u16* src[4];
  int ubase[4];
#pragma unroll
  for (int j = 0; j < 4; ++j) {
    int op = j >> 1, sw = j & 1;
    int L  = sw * 4096 + tid * 16;     // byte off within 8KB operand region
    int Ls = swz(L);
    int grow = Ls >> 6;                // 0..127
    int gcol = (Ls & 63) >> 1;
    src[j] = (op ? B + (size_t)(tile_n + grow) * K
                 : A + (size_t)(tile_m + grow) * K) + gcol;
    ubase[j] = op * 4096 + sw * 2048 + wave * 512;
  }

  int l15 = lane & 15, k16 = lane >> 4;
  int aoff[4], boff[4];
#pragma unroll
  for (int mi = 0; mi < 4; ++mi) {
    int row = wr * 64 + mi * 16 + l15;
    aoff[mi] = swz(row * 64 + k16 * 16) >> 1;
  }
#pragma unroll
  for (int ni = 0; ni < 4; ++ni) {
    int row = wc * 64 + ni * 16 + l15;
    boff[ni] = 4096 + (swz(row * 64 + k16 * 16) >> 1);
  }

  f32x4 acc[4][4];
#pragma unroll
  for (int mi = 0; mi < 4; ++mi)
#pragma unroll
    for (int ni = 0; ni < 4; ++ni) { f32x4 z = {0.f,0.f,0.f,0.f}; acc[mi][ni] = z; }

#define LDSET_A2(dst, base, h) \
  _Pragma("unroll") for (int mi = 0; mi < 2; ++mi) \
    dst[mi] = *reinterpret_cast<const short8*>(&lds[(base) + aoff[(h) * 2 + mi]]);
#define LDSET_B4(dst, base) \
  _Pragma("unroll") for (int ni = 0; ni < 4; ++ni) \
    dst[ni] = *reinterpret_cast<const short8*>(&lds[(base) + boff[ni]]);
#define MFMA_H2(h, fa, fb) \
  _Pragma("unroll") for (int mi = 0; mi < 2; ++mi) \
  _Pragma("unroll") for (int ni = 0; ni < 4; ++ni) \
    acc[(h) * 2 + mi][ni] = __builtin_amdgcn_mfma_f32_16x16x32_bf16(fa[mi], fb[ni], acc[(h) * 2 + mi][ni], 0, 0, 0);

  short8 fa0[2], fa1a[2], fa1b[2], fba[4], fbb[4];

  // prologue: stage tiles 0,1,2
#pragma unroll
  for (int j = 0; j < 4; ++j) gload16(src[j], &lds[ubase[j]]);
#pragma unroll
  for (int j = 0; j < 4; ++j) gload16(src[j] + 32, &lds[8192 + ubase[j]]);
#pragma unroll
  for (int j = 0; j < 4; ++j) gload16(src[j] + 64, &lds[16384 + ubase[j]]);
  VMCNT8();
  BARRIER();
  LDSET_A2(fa0, 0, 0);
  LDSET_A2(fa1a, 0, 1);
  LDSET_B4(fba, 0);

#define GITER128(t, FA1C, FA1N, FBC, FBN) { \
    int nb  = (((t) + 3) & 3) * 8192; \
    int nb1 = (((t) + 1) & 3) * 8192; \
    bool st = (t) + 3 < NT; \
    int kadv = ((t) + 3) * 32; \
    if (st) { gload16(src[0] + kadv, &lds[nb + ubase[0]]); \
              gload16(src[1] + kadv, &lds[nb + ubase[1]]); } \
    MFMA_H2(0, fa0, FBC); \
    if (st) { VMCNT6(); } else if ((t) + 2 < NT) { VMCNT4(); } else { VMCNT0(); } \
    BARRIER(); \
    if ((t) + 1 < NT) { \
      LDSET_A2(fa0, nb1, 0); \
      LDSET_A2(FA1N, nb1, 1); \
      LDSET_B4(FBN, nb1); \
      __builtin_amdgcn_sched_barrier(0); \
    } \
    if (st) { gload16(src[2] + kadv, &lds[nb + ubase[2]]); \
              gload16(src[3] + kadv, &lds[nb + ubase[3]]); } \
    MFMA_H2(1, FA1C, FBC); \
  }

  for (int t = 0; t < NT; t += 2) {
    GITER128(t,     fa1a, fa1b, fba, fbb);
    GITER128(t + 1, fa1b, fa1a, fbb, fba);
  }

  int rq = (lane >> 4) * 4;
#pragma unroll
  for (int mi = 0; mi < 4; ++mi)
#pragma unroll
    for (int ni = 0; ni < 4; ++ni) {
      int col = tile_n + wc * 64 + ni * 16 + l15;
      float bv = bias ? bias[col] : 0.f;
#pragma unroll
      for (int j = 0; j < 4; ++j) {
        int row = tile_m + wr * 64 + mi * 16 + rq + j;
        if (row < M) {
          float v = acc[mi][ni][j] + bv;
          if (relu) v = fmaxf(v, 0.f);
          C[(size_t)row * N + col] = f2bf(v);
        }
      }
    }
#undef GITER128
#undef LDSET_A2
#undef LDSET_B4
#undef MFMA_H2
}

// ---------------- 128x128 GEMM (R2 structure; f32-out MLP cases) -------------
__global__ __launch_bounds__(256) void gemm_bt(
    const u16* __restrict__ A, const u16* __restrict__ B,
    float* __restrict__ Cf, u16* __restrict__ Cb,
    const float* __restrict__ bias, int M, int N, int K, int relu)
{
  __shared__ alignas(16) u16 As[128 * 32];
  __shared__ alignas(16) u16 Bs[128 * 32];
  int tid = threadIdx.x;
  int wave = tid >> 6, lane = tid & 63;
  int wr = wave >> 1, wc = wave & 1;
  int tile_m = blockIdx.y * 128, tile_n = blockIdx.x * 128;

  int sr = wave * 16 + (lane >> 2);
  int sc = (lane & 3) * 8;
  const u16* gA0 = A + (size_t)(tile_m + sr) * K + sc;
  const u16* gA1 = A + (size_t)(tile_m + 64 + sr) * K + sc;
  const u16* gB0 = B + (size_t)(tile_n + sr) * K + sc;
  const u16* gB1 = B + (size_t)(tile_n + 64 + sr) * K + sc;
  u16* lA0 = &As[wave * 512];
  u16* lA1 = &As[2048 + wave * 512];
  u16* lB0 = &Bs[wave * 512];
  u16* lB1 = &Bs[2048 + wave * 512];

  f32x4 acc[4][4];
#pragma unroll
  for (int mi = 0; mi < 4; ++mi)
#pragma unroll
    for (int ni = 0; ni < 4; ++ni) { f32x4 z = {0.f,0.f,0.f,0.f}; acc[mi][ni] = z; }

  int lrow = lane & 15, lk = (lane >> 4) * 8;

  for (int k0 = 0; k0 < K; k0 += 32) {
    gload16(gA0 + k0, lA0);
    gload16(gA1 + k0, lA1);
    gload16(gB0 + k0, lB0);
    gload16(gB1 + k0, lB1);
    __syncthreads();
    short8 af[4], bfr[4];
#pragma unroll
    for (int mi = 0; mi < 4; ++mi)
      af[mi] = *reinterpret_cast<const short8*>(&As[(wr * 64 + mi * 16 + lrow) * 32 + lk]);
#pragma unroll
    for (int ni = 0; ni < 4; ++ni)
      bfr[ni] = *reinterpret_cast<const short8*>(&Bs[(wc * 64 + ni * 16 + lrow) * 32 + lk]);
#pragma unroll
    for (int mi = 0; mi < 4; ++mi)
#pragma unroll
      for (int ni = 0; ni < 4; ++ni)
        acc[mi][ni] = __builtin_amdgcn_mfma_f32_16x16x32_bf16(af[mi], bfr[ni], acc[mi][ni], 0, 0, 0);
    __syncthreads();
  }

  int rquad = (lane >> 4) * 4;
#pragma unroll
  for (int mi = 0; mi < 4; ++mi)
#pragma unroll
    for (int ni = 0; ni < 4; ++ni) {
      int col = tile_n + wc * 64 + ni * 16 + lrow;
      float bv = bias ? bias[col] : 0.f;
#pragma unroll
      for (int j = 0; j < 4; ++j) {
        int row = tile_m + wr * 64 + mi * 16 + rquad + j;
        if (row < M) {
          float v = acc[mi][ni][j] + bv;
          if (relu) v = fmaxf(v, 0.f);
          if (Cb) Cb[(size_t)row * N + col] = f2bf(v);
          else    Cf[(size_t)row * N + col] = v;
        }
      }
    }
}

// ---------------- attention scores: a_src/a_dst [N,4] -----------------------
__global__ __launch_bounds__(256) void attn_scores(
    const u16* __restrict__ h, const float* __restrict__ asrc,
    const float* __restrict__ adst, float* __restrict__ a_s, float* __restrict__ a_d)
{
  int n = blockIdx.x;
  int hh = threadIdx.x >> 6, lane = threadIdx.x & 63;
  const u16* hr = h + (size_t)n * 8192 + hh * 2048;
  const float* as = asrc + hh * 2048;
  const float* ad = adst + hh * 2048;
  float ssum = 0.f, dsum = 0.f;
#pragma unroll
  for (int i = 0; i < 4; ++i) {
    int c = lane * 8 + i * 512;
    short8 v = *reinterpret_cast<const short8*>(hr + c);
#pragma unroll
    for (int j = 0; j < 8; ++j) {
      float f = bf2f((u16)v[j]);
      ssum += f * as[c + j];
      dsum += f * ad[c + j];
    }
  }
  for (int off = 32; off; off >>= 1) {
    ssum += __shfl_down(ssum, off);
    dsum += __shfl_down(dsum, off);
  }
  if (lane == 0) { a_s[n * 4 + hh] = ssum; a_d[n * 4 + hh] = dsum; }
}

// ---------------- CSR build --------------------------------------------------
__global__ void zero_int(int* p, int n){ int i = blockIdx.x*256+threadIdx.x; if (i < n) p[i] = 0; }

__global__ void count_deg(const int* __restrict__ ei, int E, int Nn, int* __restrict__ deg){
  int e = blockIdx.x*256+threadIdx.x; if (e >= E + Nn) return;
  int d = (e < E) ? ei[E + e] : (e - E);
  atomicAdd(&deg[d], 1);
}

__global__ void scan_deg(const int* __restrict__ deg, int* __restrict__ row_st,
                         int* __restrict__ cursor, int Nn){
  __shared__ int partial[256];
  int tid = threadIdx.x;
  int chunk = (Nn + 255) / 256;
  int start = tid * chunk;
  int sum = 0;
  for (int i = 0; i < chunk; ++i) { int idx = start + i; if (idx < Nn) sum += deg[idx]; }
  partial[tid] = sum;
  __syncthreads();
  if (tid == 0) { int acc = 0; for (int i = 0; i < 256; ++i) { int t = partial[i]; partial[i] = acc; acc += t; } }
  __syncthreads();
  int acc = partial[tid];
  for (int i = 0; i < chunk; ++i) {
    int idx = start + i;
    if (idx < Nn) { row_st[idx] = acc; cursor[idx] = acc; acc += deg[idx]; }
  }
  if (tid == 255) row_st[Nn] = acc;
}

__global__ void scatter_edges(const int* __restrict__ ei, int E, int Nn,
                              int* __restrict__ cursor, int* __restrict__ srcs){
  int e = blockIdx.x*256+threadIdx.x; if (e >= E + Nn) return;
  int s = (e < E) ? ei[e]     : (e - E);
  int d = (e < E) ? ei[E + e] : (e - E);
  int pos = atomicAdd(&cursor[d], 1);
  srcs[pos] = s;
}

// ---------------- per-(node,head) edge softmax -------------------------------
__global__ void edge_softmax(const int* __restrict__ row_st, const int* __restrict__ srcs,
                             const float* __restrict__ a_s, const float* __restrict__ a_d,
                             float* __restrict__ alpha, int Nn){
  int t = blockIdx.x*256+threadIdx.x;
  if (t >= Nn * 4) return;
  int n = t >> 2, hh = t & 3;
  int b = row_st[n], e = row_st[n + 1];
  float ad = a_d[n * 4 + hh];
  float m = -1e30f;
  for (int p = b; p < e; ++p) {
    float x = a_s[srcs[p] * 4 + hh] + ad;
    x = x > 0.f ? x : 0.2f * x;
    alpha[p * 4 + hh] = x;
    m = fmaxf(m, x);
  }
  float ssum = 0.f;
  for (int p = b; p < e; ++p) {
    float ex = expf(alpha[p * 4 + hh] - m);
    alpha[p * 4 + hh] = ex;
    ssum += ex;
  }
  float inv = 1.f / (ssum + 1e-16f);
  for (int p = b; p < e; ++p) alpha[p * 4 + hh] *= inv;
}

// ---------------- aggregation: out[n, hh*2048:] = sum alpha*h[src] + bias ----
__global__ __launch_bounds__(256) void aggregate(
    const u16* __restrict__ h, const float* __restrict__ alpha,
    const int* __restrict__ row_st, const int* __restrict__ srcs,
    const float* __restrict__ bias, u16* __restrict__ out)
{
  int n = blockIdx.x, hh = blockIdx.y, tid = threadIdx.x;
  int c0 = hh * 2048 + tid * 8;
  float acc[8];
#pragma unroll
  for (int q = 0; q < 8; ++q) acc[q] = 0.f;
  int b = row_st[n], e = row_st[n + 1];
  for (int p = b; p < e; ++p) {
    int s = srcs[p];
    float a = alpha[p * 4 + hh];
    short8 v = *reinterpret_cast<const short8*>(h + (size_t)s * 8192 + c0);
#pragma unroll
    for (int q = 0; q < 8; ++q) acc[q] += a * bf2f((u16)v[q]);
  }
  short8 ov;
#pragma unroll
  for (int q = 0; q < 8; ++q) ov[q] = (short)f2bf(acc[q] + bias[c0 + q]);
  *reinterpret_cast<short8*>(out + (size_t)n * 8192 + c0) = ov;
}

// ---------------- mean pool over sorted batch --------------------------------
__global__ __launch_bounds__(256) void pool_mean(
    const u16* __restrict__ hf, const int* __restrict__ batch,
    u16* __restrict__ g, int Nn)
{
  int gid = blockIdx.x, tid = threadIdx.x;
  int s1, s2;
  { int l = 0, h = Nn; while (l < h) { int m = (l + h) >> 1; if (batch[m] < gid) l = m + 1; else h = m; } s1 = l; }
  { int l = 0, h = Nn; while (l < h) { int m = (l + h) >> 1; if (batch[m] < gid + 1) l = m + 1; else h = m; } s2 = l; }
  float inv = 1.f / fmaxf((float)(s2 - s1), 1.f);
  float acc[8];
#pragma unroll
  for (int q = 0; q < 8; ++q) acc[q] = 0.f;
  for (int r = s1; r < s2; ++r) {
    short8 v = *reinterpret_cast<const short8*>(hf + (size_t)r * 2048 + tid * 8);
#pragma unroll
    for (int q = 0; q < 8; ++q) acc[q] += bf2f((u16)v[q]);
  }
  short8 ov;
#pragma unroll
  for (int q = 0; q < 8; ++q) ov[q] = (short)f2bf(acc[q] * inv);
  *reinterpret_cast<short8*>(g + (size_t)gid * 2048 + tid * 8) = ov;
}

// ---------------- layernorm over 768 ----------------------------------------
__global__ __launch_bounds__(256) void layernorm_768(
    const float* __restrict__ x, const float* __restrict__ gam,
    const float* __restrict__ bet, float* __restrict__ out)
{
  int row = blockIdx.x, tid = threadIdx.x, lane = tid & 63, w = tid >> 6;
  __shared__ float sh[8];
  float v0 = x[row * 768 + tid];
  float v1 = x[row * 768 + 256 + tid];
  float v2 = x[row * 768 + 512 + tid];
  float s = v0 + v1 + v2;
  for (int off = 32; off; off >>= 1) s += __shfl_down(s, off);
  if (lane == 0) sh[w] = s;
  __syncthreads();
  if (tid == 0) sh[4] = (sh[0] + sh[1] + sh[2] + sh[3]) / 768.f;
  __syncthreads();
  float mu = sh[4];
  float d0 = v0 - mu, d1 = v1 - mu, d2 = v2 - mu;
  float q = d0 * d0 + d1 * d1 + d2 * d2;
  for (int off = 32; off; off >>= 1) q += __shfl_down(q, off);
  if (lane == 0) sh[w] = q;
  __syncthreads();
  if (tid == 0) sh[5] = rsqrtf((sh[0] + sh[1] + sh[2] + sh[3]) / 768.f + 1e-5f);
  __syncthreads();
  float rstd = sh[5];
  out[row * 768 + tid]       = d0 * rstd * gam[tid]       + bet[tid];
  out[row * 768 + 256 + tid] = d1 * rstd * gam[256 + tid] + bet[256 + tid];
  out[row * 768 + 512 + tid] = d2 * rstd * gam[512 + tid] + bet[512 + tid];
}

// ============================================================================
extern "C" void kernel_launch(void* const* d_in, const int* in_sizes, int n_in,
                              void* d_out, int out_size, void* d_ws, size_t ws_size,
                              hipStream_t stream)
{
  const float* x     = (const float*)d_in[0];
  const int*   ei    = (const int*)d_in[1];
  const int*   batch = (const int*)d_in[2];
  const float* W[3]   = {(const float*)d_in[3], (const float*)d_in[9],  (const float*)d_in[15]};
  const float* asr[3] = {(const float*)d_in[4], (const float*)d_in[10], (const float*)d_in[16]};
  const float* ads[3] = {(const float*)d_in[5], (const float*)d_in[11], (const float*)d_in[17]};
  const float* bc[3]  = {(const float*)d_in[6], (const float*)d_in[12], (const float*)d_in[18]};
  const float* Wh[3]  = {(const float*)d_in[7], (const float*)d_in[13], (const float*)d_in[19]};
  const float* bh[3]  = {(const float*)d_in[8], (const float*)d_in[14], (const float*)d_in[20]};
  const float* Wm1 = (const float*)d_in[21];
  const float* bm1 = (const float*)d_in[22];
  const float* Wm2 = (const float*)d_in[23];
  const float* bm2 = (const float*)d_in[24];
  const float* lng = (const float*)d_in[25];
  const float* lnb = (const float*)d_in[26];
  float* out = (float*)d_out;

  int Nn = in_sizes[2];        // 5000
  int E  = in_sizes[1] / 2;    // 15000
  int ET = E + Nn;

  char* base = (char*)d_ws;
  size_t off = 0;
  auto alloc = [&](size_t b) -> char* { char* p = base + off; off = (off + b + 255) & ~(size_t)255; return p; };
  u16*  xb    = (u16*)alloc((size_t)Nn * 320 * 2);
  u16*  Wt    = (u16*)alloc((size_t)8192 * 2048 * 2);
  u16*  Wht   = (u16*)alloc((size_t)8192 * 2048 * 2);
  u16*  hb    = (u16*)alloc((size_t)Nn * 8192 * 2);
  u16*  ob    = (u16*)alloc((size_t)Nn * 8192 * 2);
  u16*  xlb   = (u16*)alloc((size_t)Nn * 2048 * 2);
  float* a_s  = (float*)alloc((size_t)Nn * 4 * 4);
  float* a_d  = (float*)alloc((size_t)Nn * 4 * 4);
  float* alpha= (float*)alloc((size_t)ET * 4 * 4);
  int*  deg   = (int*)alloc((size_t)(Nn + 1) * 4);
  int*  rowst = (int*)alloc((size_t)(Nn + 1) * 4);
  int*  cursor= (int*)alloc((size_t)(Nn + 1) * 4);
  int*  srcs  = (int*)alloc((size_t)ET * 4);
  u16*  g     = (u16*)alloc((size_t)128 * 2048 * 2);
  u16*  g2    = (u16*)alloc((size_t)128 * 2048 * 2);
  float* preln= (float*)alloc((size_t)128 * 768 * 4);

  // ---- CSR by dst (self loops appended) ----
  zero_int<<<(Nn + 255) / 256, 256, 0, stream>>>(deg, Nn);
  count_deg<<<(ET + 255) / 256, 256, 0, stream>>>(ei, E, Nn, deg);
  scan_deg<<<1, 256, 0, stream>>>(deg, rowst, cursor, Nn);
  scatter_edges<<<(ET + 255) / 256, 256, 0, stream>>>(ei, E, Nn, cursor, srcs);

  // ---- input cast (pad K 300->320) ----
  cast_pad<<<(Nn * 320 + 255) / 256, 256, 0, stream>>>(x, xb, Nn, 300, 320);

  const u16* act = xb;
  int mt256 = (Nn + 255) / 256;   // 20
  int mt128 = (Nn + 127) / 128;   // 40
  for (int l = 0; l < 3; ++l) {
    int Kp = (l == 0) ? 320 : 2048;
    transpose_cast<<<dim3(Kp / 32, 8192 / 32), 256, 0, stream>>>(W[l], Wt, (l == 0) ? 300 : 2048, 8192, Kp);
    if (l == 1)   // within-run A/B: L1 conv on 128p vs L0/L2 on 256-pf3
      gemm128p<<<dim3(64, mt128), 256, 0, stream>>>(act, Wt, hb, nullptr, Nn, 8192, Kp, 0);
    else
      gemm256<<<dim3(32, mt256), 512, 0, stream>>>(act, Wt, hb, nullptr, Nn, 8192, Kp, 0);
    attn_scores<<<Nn, 256, 0, stream>>>(hb, asr[l], ads[l], a_s, a_d);
    edge_softmax<<<(Nn * 4 + 255) / 256, 256, 0, stream>>>(rowst, srcs, a_s, a_d, alpha, Nn);
    aggregate<<<dim3(Nn, 4), 256, 0, stream>>>(hb, alpha, rowst, srcs, bc[l], ob);
    transpose_cast<<<dim3(8192 / 32, 2048 / 32), 256, 0, stream>>>(Wh[l], Wht, 8192, 2048, 8192);
    gemm128p<<<dim3(16, mt128), 256, 0, stream>>>(ob, Wht, xlb, bh[l], Nn, 2048, 8192, (l < 2) ? 1 : 0);
    act = xlb;
  }

  // ---- mean pool + MLP + LN ----
  pool_mean<<<128, 256, 0, stream>>>(xlb, batch, g, Nn);
  transpose_cast<<<dim3(2048 / 32, 2048 / 32), 256, 0, stream>>>(Wm1, Wt, 2048, 2048, 2048);
  gemm_bt<<<dim3(16, 1), 256, 0, stream>>>(g, Wt, nullptr, g2, bm1, 128, 2048, 2048, 1);
  transpose_cast<<<dim3(2048 / 32, 768 / 32), 256, 0, stream>>>(Wm2, Wht, 2048, 768, 2048);
  gemm_bt<<<dim3(6, 1), 256, 0, stream>>>(g2, Wht, preln, nullptr, bm2, 128, 768, 2048, 0);
  layernorm_768<<<128, 256, 0, stream>>>(preln, lng, lnb, out);
}